// Round 16
// baseline (586.161 us; speedup 1.0000x reference)
//
#include <hip/hip_runtime.h>

#define CCH 256      // channels
#define KTOT 512     // mean(256) ++ x_dst(256)
#define GM_BM 128    // rows per block in GEMM
#define GM_BK 32     // K-step (elems; 64 B per row = 4 slots of 16 B)
#define GM_TH 512    // threads (8 waves: 2 row-groups x 4 col-groups)
#define A_BUF_BYTES (GM_BM * GM_BK * 2)   // 8192  B per A buffer
#define B_BUF_BYTES (CCH * GM_BK * 2)     // 16384 B per B buffer
#define SCB 2048     // scan elems per block (256 thr x 8)

using f32x4  = __attribute__((ext_vector_type(4))) float;
using bf16x8 = __attribute__((ext_vector_type(8))) short;
using u16x4  = __attribute__((ext_vector_type(4))) unsigned short;

__device__ __forceinline__ unsigned short f2bf(float f) {
    union { float f; unsigned u; } v; v.f = f;
    unsigned r = v.u + 0x7FFFu + ((v.u >> 16) & 1u);   // RNE
    return (unsigned short)(r >> 16);
}
__device__ __forceinline__ float bf2f(short h) {
    union { unsigned u; float f; } v;
    v.u = ((unsigned)(unsigned short)h) << 16;
    return v.f;
}
__device__ __forceinline__ void gload16(const void* g, void* l) {
    __builtin_amdgcn_global_load_lds(
        (const __attribute__((address_space(1))) unsigned int*)g,
        (__attribute__((address_space(3))) unsigned int*)l, 16, 0, 0);
}

// ---------------- fp32 -> bf16 convert (both matrices via blockIdx.y) ----------------
__global__ __launch_bounds__(256)
void cvt_bf16(const float* __restrict__ x0, unsigned short* __restrict__ y0,
              const float* __restrict__ x1, unsigned short* __restrict__ y1, long n) {
    const float* x        = blockIdx.y ? x1 : x0;
    unsigned short* y     = blockIdx.y ? y1 : y0;
    long i = ((long)blockIdx.x * 256 + threadIdx.x) * 8;
    if (i >= n) return;
    float4 a = *(const float4*)(x + i);
    float4 b = *(const float4*)(x + i + 4);
    bf16x8 pk;
    pk[0]=(short)f2bf(a.x); pk[1]=(short)f2bf(a.y); pk[2]=(short)f2bf(a.z); pk[3]=(short)f2bf(a.w);
    pk[4]=(short)f2bf(b.x); pk[5]=(short)f2bf(b.y); pk[6]=(short)f2bf(b.z); pk[7]=(short)f2bf(b.w);
    *(bf16x8*)(y + i) = pk;
}

// ------- W concat + bf16: grid.y encodes (dir, layer) -------
__global__ __launch_bounds__(256)
void cvt_wcat(const float* __restrict__ Wl0, const float* __restrict__ Wr0,
              unsigned short* __restrict__ o0,
              const float* __restrict__ Wl1, const float* __restrict__ Wr1,
              unsigned short* __restrict__ o1) {
    const int l   = blockIdx.y & 1;
    const int dir = blockIdx.y >> 1;
    const float* wl = (dir ? Wl1 : Wl0) + (size_t)l * CCH * CCH;
    const float* wr = (dir ? Wr1 : Wr0) + (size_t)l * CCH * CCH;
    unsigned short* o = (dir ? o1 : o0) + (size_t)l * CCH * KTOT;
    int idx = (blockIdx.x * 256 + threadIdx.x) * 8;     // 0..65528
    int col = idx >> 8, k = idx & 255;
    {
        float4 a = *(const float4*)(wl + col * CCH + k);
        float4 b = *(const float4*)(wl + col * CCH + k + 4);
        bf16x8 pk;
        pk[0]=(short)f2bf(a.x); pk[1]=(short)f2bf(a.y); pk[2]=(short)f2bf(a.z); pk[3]=(short)f2bf(a.w);
        pk[4]=(short)f2bf(b.x); pk[5]=(short)f2bf(b.y); pk[6]=(short)f2bf(b.z); pk[7]=(short)f2bf(b.w);
        *(bf16x8*)(o + (size_t)col * KTOT + k) = pk;
    }
    {
        float4 a = *(const float4*)(wr + col * CCH + k);
        float4 b = *(const float4*)(wr + col * CCH + k + 4);
        bf16x8 pk;
        pk[0]=(short)f2bf(a.x); pk[1]=(short)f2bf(a.y); pk[2]=(short)f2bf(a.z); pk[3]=(short)f2bf(a.w);
        pk[4]=(short)f2bf(b.x); pk[5]=(short)f2bf(b.y); pk[6]=(short)f2bf(b.z); pk[7]=(short)f2bf(b.w);
        *(bf16x8*)(o + (size_t)col * KTOT + CCH + k) = pk;
    }
}

// ---------------- CSR build (both directions via blockIdx.y) ----------------
__global__ __launch_bounds__(256)
void hist_kernel(const int* __restrict__ ei0, int* __restrict__ c0,
                 const int* __restrict__ ei1, int* __restrict__ c1, int E) {
    const int* ei = blockIdx.y ? ei1 : ei0;
    int* cnt      = blockIdx.y ? c1  : c0;
    int e = blockIdx.x * blockDim.x + threadIdx.x;
    if (e < E) atomicAdd(&cnt[ei[E + e]], 1);
}

__global__ __launch_bounds__(256)
void scan_part(const int* __restrict__ c0, int* __restrict__ b0,
               const int* __restrict__ c1, int* __restrict__ b1, int N) {
    const int* cnt = blockIdx.y ? c1 : c0;
    int* bsum      = blockIdx.y ? b1 : b0;
    __shared__ int sw[4];
    int t = threadIdx.x;
    int base = blockIdx.x * SCB + t * 8;
    int s = 0;
#pragma unroll
    for (int j = 0; j < 8; ++j) { int idx = base + j; s += (idx < N) ? cnt[idx] : 0; }
    for (int m = 1; m < 64; m <<= 1) s += __shfl_xor(s, m);
    if ((t & 63) == 0) sw[t >> 6] = s;
    __syncthreads();
    if (t == 0) bsum[blockIdx.x] = sw[0] + sw[1] + sw[2] + sw[3];
}

__global__ __launch_bounds__(256)
void scan_bsum(int* __restrict__ ba, int* __restrict__ bb, int nb) {
    int* b = blockIdx.x ? bb : ba;
    __shared__ int s[256];
    int t = threadIdx.x;
    int v = (t < nb) ? b[t] : 0;
    s[t] = v;
    __syncthreads();
    for (int o = 1; o < 256; o <<= 1) {
        int u = 0;
        if (t >= o) u = s[t - o];
        __syncthreads();
        if (t >= o) s[t] += u;
        __syncthreads();
    }
    if (t < nb) b[t] = s[t] - v;   // exclusive
}

__global__ __launch_bounds__(256)
void scan_apply(const int* __restrict__ c0, const int* __restrict__ b0,
                int* __restrict__ r0, int* __restrict__ cur0,
                const int* __restrict__ c1, const int* __restrict__ b1,
                int* __restrict__ r1, int* __restrict__ cur1, int N, int E) {
    const int* cnt  = blockIdx.y ? c1 : c0;
    const int* bsum = blockIdx.y ? b1 : b0;
    int* rowstart   = blockIdx.y ? r1 : r0;
    int* cursor     = blockIdx.y ? cur1 : cur0;
    __shared__ int sw[4];
    int t = threadIdx.x;
    int base = blockIdx.x * SCB + t * 8;
    int v[8]; int s = 0;
#pragma unroll
    for (int j = 0; j < 8; ++j) { int idx = base + j; v[j] = (idx < N) ? cnt[idx] : 0; s += v[j]; }
    int own = s;
    for (int m = 1; m < 64; m <<= 1) {
        int u = __shfl_up(s, m);
        if ((t & 63) >= m) s += u;
    }
    if ((t & 63) == 63) sw[t >> 6] = s;
    __syncthreads();
    int w = t >> 6, woff = 0;
    if (w > 0) woff += sw[0];
    if (w > 1) woff += sw[1];
    if (w > 2) woff += sw[2];
    int excl = bsum[blockIdx.x] + woff + s - own;
#pragma unroll
    for (int j = 0; j < 8; ++j) {
        int idx = base + j;
        if (idx < N) { rowstart[idx] = excl; excl += v[j]; cursor[idx] = 0; }
    }
    if (blockIdx.x == 0 && t == 0) rowstart[N] = E;
}

__global__ __launch_bounds__(256)
void fill_kernel(const int* __restrict__ ei0, const int* __restrict__ r0,
                 int* __restrict__ cur0, int* __restrict__ e0,
                 const int* __restrict__ ei1, const int* __restrict__ r1,
                 int* __restrict__ cur1, int* __restrict__ e1, int E) {
    const int* ei       = blockIdx.y ? ei1 : ei0;
    const int* rowstart = blockIdx.y ? r1  : r0;
    int* cursor         = blockIdx.y ? cur1 : cur0;
    int* elist          = blockIdx.y ? e1  : e0;
    int e = blockIdx.x * blockDim.x + threadIdx.x;
    if (e < E) {
        int dst = ei[E + e];
        int p = atomicAdd(&cursor[dst], 1);
        elist[rowstart[dst] + p] = ei[e];
    }
}

// ------------- gather + mean (bf16), both directions in one dispatch -------------
__global__ __launch_bounds__(256)
void gather_mean(const unsigned short* __restrict__ xs0, const int* __restrict__ rs0,
                 const int* __restrict__ el0, unsigned short* __restrict__ mn0,
                 const unsigned short* __restrict__ xs1, const int* __restrict__ rs1,
                 const int* __restrict__ el1, unsigned short* __restrict__ mn1, int N) {
    const unsigned short* xsrc = blockIdx.y ? xs1 : xs0;
    const int* rowstart        = blockIdx.y ? rs1 : rs0;
    const int* elist           = blockIdx.y ? el1 : el0;
    unsigned short* mean       = blockIdx.y ? mn1 : mn0;
    int node = (blockIdx.x * blockDim.x + threadIdx.x) >> 5;
    int ln   = threadIdx.x & 31;
    if (node >= N) return;
    int lo = rowstart[node], hi = rowstart[node + 1];
    float a[8] = {0.f,0.f,0.f,0.f,0.f,0.f,0.f,0.f};
    for (int i = lo; i < hi; ++i) {
        int s = elist[i];
        bf16x8 v = *((const bf16x8*)(xsrc + (size_t)s * CCH) + ln);
#pragma unroll
        for (int j = 0; j < 8; ++j) a[j] += bf2f(v[j]);
    }
    float r = (hi > lo) ? 1.0f / (float)(hi - lo) : 0.0f;
    bf16x8 pk;
#pragma unroll
    for (int j = 0; j < 8; ++j) pk[j] = (short)f2bf(a[j] * r);
    *((bf16x8*)(mean + (size_t)node * CCH) + ln) = pk;
}

// ------- fused: h = LNReLU( [mean|xdst] @ Bcat^T + bl ); both directions via blockIdx.y -------
// r13 pipeline (3-deep counted vmcnt + rule-#18 fence; proven 148us) with a NEW epilogue:
// normalized outputs staged in LDS (obuf, reusing pipeline LDS) then stored fully
// coalesced (16B/lane contiguous). r13/r15 counters showed WRITE_SIZE 287MB vs
// 102/205MB logical -> sub-line scattered stores were RMW-amplified at L2/HBM.
// NOT kept from r14 (regressed): XCD swizzle (L3-fit working set, m160), setprio
// (barrier-synced GEMM, m190), heterogeneous 4-deep (null).
__global__ __launch_bounds__(GM_TH, 4)
void sage_gemm_ln(const unsigned short* __restrict__ mean0,
                  const unsigned short* __restrict__ xdst0,
                  const unsigned short* __restrict__ Bc0,
                  const float* __restrict__ bl0,
                  const float* __restrict__ gm0, const float* __restrict__ bt0,
                  float* __restrict__ outf0, unsigned short* __restrict__ outb0,
                  const unsigned short* __restrict__ mean1,
                  const unsigned short* __restrict__ xdst1,
                  const unsigned short* __restrict__ Bc1,
                  const float* __restrict__ bl1,
                  const float* __restrict__ gm1, const float* __restrict__ bt1,
                  float* __restrict__ outf1, unsigned short* __restrict__ outb1,
                  int Nrows)
{
    const int dir = blockIdx.y;
    const unsigned short* mean = dir ? mean1 : mean0;
    const unsigned short* xdst = dir ? xdst1 : xdst0;
    const unsigned short* Bcat = dir ? Bc1   : Bc0;
    const float* bl    = dir ? bl1 : bl0;
    const float* gamma = dir ? gm1 : gm0;
    const float* beta  = dir ? bt1 : bt0;
    float* outf          = dir ? outf1 : outf0;
    unsigned short* outb = dir ? outb1 : outb0;

    // 72 KB unified LDS: K-loop = As (3x8K) ++ Bs (3x16K); epilogue = red(4K) ++ obuf(64K)
    __shared__ __align__(16) char smem[73728];
    char* Asb = smem;                       // A buffers
    char* Bsb = smem + 3 * A_BUF_BYTES;     // B buffers

    const int tid  = threadIdx.x;
    const int lane = tid & 63;
    const int wr   = tid >> 8;                 // 0..1
    const int wc   = (tid >> 6) & 3;           // 0..3
    const int cl   = lane & 15;
    const int g    = lane >> 4;                // 0..3 -> k-chunk
    const long brow = (long)blockIdx.x * GM_BM;

    f32x4 acc[4][4];
#pragma unroll
    for (int m = 0; m < 4; ++m)
#pragma unroll
        for (int n = 0; n < 4; ++n) acc[m][n] = (f32x4){0.f, 0.f, 0.f, 0.f};

    // per-thread staging coords (constant across steps)
    const int rowA = tid >> 2, slA = tid & 3;               // 1 A-chunk/thread
    long growA = brow + rowA; if (growA > (long)Nrows - 1) growA = (long)Nrows - 1;
    const int swzA = ((slA ^ ((rowA >> 1) & 3)) << 3);
    const int colB0 = tid >> 2,          slB0 = tid & 3;    // 2 B-chunks/thread
    const int colB1 = (tid + 512) >> 2,  slB1 = tid & 3;
    const int swzB0 = ((slB0 ^ ((colB0 >> 1) & 3)) << 3);
    const int swzB1 = ((slB1 ^ ((colB1 >> 1) & 3)) << 3);

#define STAGE(buf, t)                                                              \
    {                                                                              \
        const int kb_ = (t) * GM_BK;                                               \
        const unsigned short* asrc_ = (kb_ < CCH) ? mean : xdst;                   \
        const int akk_ = kb_ & (CCH - 1);                                          \
        gload16(asrc_ + growA * CCH + akk_ + swzA,                                 \
                Asb + (buf) * A_BUF_BYTES + tid * 16);                             \
        gload16(Bcat + (size_t)colB0 * KTOT + kb_ + swzB0,                         \
                Bsb + (buf) * B_BUF_BYTES + tid * 16);                             \
        gload16(Bcat + (size_t)colB1 * KTOT + kb_ + swzB1,                         \
                Bsb + (buf) * B_BUF_BYTES + (tid + 512) * 16);                     \
    }

    const int nsteps = KTOT / GM_BK;   // 16
    STAGE(0, 0);
    STAGE(1, 1);
    asm volatile("s_waitcnt vmcnt(3)" ::: "memory");   // buf0's 3 loads landed
    __builtin_amdgcn_s_barrier();
    __builtin_amdgcn_sched_barrier(0);
    for (int t = 0; t < nsteps; ++t) {
        if (t + 2 < nsteps) STAGE((t + 2) % 3, t + 2);   // stays in flight across barrier
        const char* Ab = Asb + (t % 3) * A_BUF_BYTES;
        const char* Bb = Bsb + (t % 3) * B_BUF_BYTES;
        bf16x8 a[4], b[4];
#pragma unroll
        for (int m = 0; m < 4; ++m) {
            int row = wr * 64 + m * 16 + cl;
            int slot = g ^ ((row >> 1) & 3);
            a[m] = *(const bf16x8*)(Ab + row * 64 + slot * 16);
        }
#pragma unroll
        for (int n = 0; n < 4; ++n) {
            int col = wc * 64 + n * 16 + cl;
            int slot = g ^ ((col >> 1) & 3);
            b[n] = *(const bf16x8*)(Bb + col * 64 + slot * 16);
        }
#pragma unroll
        for (int m = 0; m < 4; ++m)
#pragma unroll
            for (int n = 0; n < 4; ++n)
                acc[m][n] = __builtin_amdgcn_mfma_f32_16x16x32_bf16(a[m], b[n], acc[m][n], 0, 0, 0);
        // race fence (rule #18): this wave's ds_reads must have RETURNED before barrier
        asm volatile("s_waitcnt lgkmcnt(0)" ::: "memory");
        __builtin_amdgcn_sched_barrier(0);
        // counted wait: buf(t+1)'s loads retired; buf(t+2)'s may stay in flight
        if (t < nsteps - 2) asm volatile("s_waitcnt vmcnt(3)" ::: "memory");
        else                asm volatile("s_waitcnt vmcnt(0)" ::: "memory");
        __builtin_amdgcn_s_barrier();
        __builtin_amdgcn_sched_barrier(0);
    }
#undef STAGE

    // ---- epilogue: +bias, cross-wave LayerNorm, ReLU, COALESCED store via LDS ----
    float p1[4][4], p2[4][4];   // [m][j]
#pragma unroll
    for (int m = 0; m < 4; ++m)
#pragma unroll
        for (int j = 0; j < 4; ++j) { p1[m][j] = 0.f; p2[m][j] = 0.f; }
#pragma unroll
    for (int n = 0; n < 4; ++n) {
        float bv = bl[wc * 64 + n * 16 + cl];
#pragma unroll
        for (int m = 0; m < 4; ++m)
#pragma unroll
            for (int j = 0; j < 4; ++j) {
                float v = acc[m][n][j] + bv;
                acc[m][n][j] = v;
                p1[m][j] += v;
                p2[m][j] += v * v;
            }
    }
#pragma unroll
    for (int msk = 1; msk < 16; msk <<= 1) {
#pragma unroll
        for (int m = 0; m < 4; ++m)
#pragma unroll
            for (int j = 0; j < 4; ++j) {
                p1[m][j] += __shfl_xor(p1[m][j], msk);
                p2[m][j] += __shfl_xor(p2[m][j], msk);
            }
    }
    float2* red = (float2*)smem;            // 4 KB stats table
    float*  obuf = (float*)(smem + 4096);   // 64 KB staging, 64 rows x 256 cols
    if (cl == 0) {
#pragma unroll
        for (int m = 0; m < 4; ++m)
#pragma unroll
            for (int j = 0; j < 4; ++j) {
                int rl = wr * 64 + m * 16 + g * 4 + j;
                red[rl * 4 + wc] = make_float2(p1[m][j], p2[m][j]);
            }
    }
    __syncthreads();

    float gmv[4], btv[4];
#pragma unroll
    for (int n = 0; n < 4; ++n) {
        gmv[n] = gamma[wc * 64 + n * 16 + cl];
        btv[n] = beta[wc * 64 + n * 16 + cl];
    }

    for (int pass = 0; pass < 2; ++pass) {
        if (wr == pass) {
#pragma unroll
            for (int m = 0; m < 4; ++m) {
#pragma unroll
                for (int j = 0; j < 4; ++j) {
                    int rl = wr * 64 + m * 16 + g * 4 + j;
                    f32x4 u0 = *(const f32x4*)&red[rl * 4 + 0];
                    f32x4 u1 = *(const f32x4*)&red[rl * 4 + 2];
                    float s1 = u0[0] + u0[2] + u1[0] + u1[2];
                    float s2 = u0[1] + u0[3] + u1[1] + u1[3];
                    float mu = s1 * (1.0f / CCH);
                    float var = s2 * (1.0f / CCH) - mu * mu;
                    float rsd = rsqrtf(var + 1e-5f);
                    int orow = m * 16 + g * 4 + j;    // row within pass block
#pragma unroll
                    for (int n = 0; n < 4; ++n) {
                        float v = (acc[m][n][j] - mu) * rsd * gmv[n] + btv[n];
                        obuf[orow * CCH + wc * 64 + n * 16 + cl] = fmaxf(v, 0.f);
                    }
                }
            }
        }
        __syncthreads();
        // store phase: 512 threads x 8 iters x 16B contiguous = 64KB, fully coalesced
        const long prow0 = brow + pass * 64;
#pragma unroll
        for (int it = 0; it < 8; ++it) {
            int idx = tid + it * 512;          // 0..4095
            int row = idx >> 6;                // 0..63
            int c4  = (idx & 63) * 4;          // col start
            long r = prow0 + row;
            if (r < Nrows) {
                f32x4 v = *(const f32x4*)(obuf + (size_t)idx * 4);
                if (outf) *(f32x4*)(outf + r * CCH + c4) = v;
                if (outb) {
                    u16x4 pk;
                    pk[0] = f2bf(v[0]); pk[1] = f2bf(v[1]);
                    pk[2] = f2bf(v[2]); pk[3] = f2bf(v[3]);
                    *(u16x4*)(outb + r * CCH + c4) = pk;
                }
            }
        }
        __syncthreads();   // obuf reuse by next pass
    }
}

extern "C" void kernel_launch(void* const* d_in, const int* in_sizes, int n_in,
                              void* d_out, int out_size, void* d_ws, size_t ws_size,
                              hipStream_t stream) {
    const float* x_user = (const float*)d_in[0];
    const float* x_item = (const float*)d_in[1];
    const int*   ei_u2i = (const int*)d_in[2];
    const int*   ei_i2u = (const int*)d_in[3];
    const float* Wl_u2i = (const float*)d_in[4];
    const float* bl_u2i = (const float*)d_in[5];
    const float* Wr_u2i = (const float*)d_in[6];
    const float* Wl_i2u = (const float*)d_in[7];
    const float* bl_i2u = (const float*)d_in[8];
    const float* Wr_i2u = (const float*)d_in[9];
    const float* g_user = (const float*)d_in[10];
    const float* b_user = (const float*)d_in[11];
    const float* g_item = (const float*)d_in[12];
    const float* b_item = (const float*)d_in[13];

    const int N = in_sizes[0] / CCH;
    const int E = in_sizes[2] / 2;
    const size_t NC = (size_t)N * CCH;
    const int nb = (N + SCB - 1) / SCB;

    // workspace layout (~210 MB)
    char* p = (char*)d_ws;
    unsigned short* xb_u   = (unsigned short*)p; p += NC * sizeof(unsigned short);
    unsigned short* xb_i   = (unsigned short*)p; p += NC * sizeof(unsigned short);
    unsigned short* mean_i = (unsigned short*)p; p += NC * sizeof(unsigned short);
    unsigned short* mean_u = (unsigned short*)p; p += NC * sizeof(unsigned short);
    unsigned short* wc_u2i = (unsigned short*)p; p += (size_t)2 * CCH * KTOT * sizeof(unsigned short);
    unsigned short* wc_i2u = (unsigned short*)p; p += (size_t)2 * CCH * KTOT * sizeof(unsigned short);
    int* cnt_i  = (int*)p; p += (size_t)N * sizeof(int);   // doubles as fill cursor
    int* cnt_u  = (int*)p; p += (size_t)N * sizeof(int);   // contiguous with cnt_i (one memset)
    int* rs_i   = (int*)p; p += (size_t)(N + 1) * sizeof(int);
    int* rs_u   = (int*)p; p += (size_t)(N + 1) * sizeof(int);
    int* el_i   = (int*)p; p += (size_t)E * sizeof(int);
    int* el_u   = (int*)p; p += (size_t)E * sizeof(int);
    int* bs_i   = (int*)p; p += 256 * sizeof(int);
    int* bs_u   = (int*)p; p += 256 * sizeof(int);

    float* out_user = (float*)d_out;
    float* out_item = out_user + NC;

    const int eb = (E + 255) / 256;
    const int cb = (int)((NC / 8 + 255) / 256);
    const int gm_blocks = (N + GM_BM - 1) / GM_BM;
    const int gw_blocks = (int)(((size_t)N * 32 + 255) / 256);   // half-wave per node

    // ---- CSR build (merged: one dispatch per pass) ----
    hipMemsetAsync(cnt_i, 0, (size_t)2 * N * sizeof(int), stream);   // cnt_i + cnt_u
    hist_kernel<<<dim3(eb, 2), 256, 0, stream>>>(ei_u2i, cnt_i, ei_i2u, cnt_u, E);
    scan_part<<<dim3(nb, 2), 256, 0, stream>>>(cnt_i, bs_i, cnt_u, bs_u, N);
    scan_bsum<<<2, 256, 0, stream>>>(bs_i, bs_u, nb);
    scan_apply<<<dim3(nb, 2), 256, 0, stream>>>(cnt_i, bs_i, rs_i, cnt_i,
                                                cnt_u, bs_u, rs_u, cnt_u, N, E);
    fill_kernel<<<dim3(eb, 2), 256, 0, stream>>>(ei_u2i, rs_i, cnt_i, el_i,
                                                 ei_i2u, rs_u, cnt_u, el_u, E);

    // ---- weight concat + bf16 (once) ----
    cvt_wcat<<<dim3(32, 4), 256, 0, stream>>>(Wl_u2i, Wr_u2i, wc_u2i,
                                              Wl_i2u, Wr_i2u, wc_i2u);

    // ---- bf16 copies of inputs ----
    cvt_bf16<<<dim3(cb, 2), 256, 0, stream>>>(x_user, xb_u, x_item, xb_i, (long)NC);

    for (int l = 0; l < 2; ++l) {
        const size_t wl = (size_t)l * CCH * KTOT;
        gather_mean<<<dim3(gw_blocks, 2), 256, 0, stream>>>(
            xb_u, rs_i, el_i, mean_i,
            xb_i, rs_u, el_u, mean_u, N);
        if (l == 0) {
            sage_gemm_ln<<<dim3(gm_blocks, 2), GM_TH, 0, stream>>>(
                mean_i, xb_i, wc_u2i + wl, bl_u2i + l * CCH, g_item + l * CCH, b_item + l * CCH,
                nullptr, xb_i,
                mean_u, xb_u, wc_i2u + wl, bl_i2u + l * CCH, g_user + l * CCH, b_user + l * CCH,
                nullptr, xb_u, N);
        } else {
            sage_gemm_ln<<<dim3(gm_blocks, 2), GM_TH, 0, stream>>>(
                mean_i, xb_i, wc_u2i + wl, bl_u2i + l * CCH, g_item + l * CCH, b_item + l * CCH,
                out_item, nullptr,
                mean_u, xb_u, wc_i2u + wl, bl_i2u + l * CCH, g_user + l * CCH, b_user + l * CCH,
                out_user, nullptr, N);
        }
    }
}

// Round 17
// 544.476 us; speedup vs baseline: 1.0766x; 1.0766x over previous
//
#include <hip/hip_runtime.h>

#define CCH 256      // channels
#define KTOT 512     // mean(256) ++ x_dst(256)
#define GM_BM 128    // rows per block in GEMM
#define GM_BK 32     // K-step (elems; 64 B per row = 4 slots of 16 B)
#define GM_TH 512    // threads (8 waves: 2 row-groups x 4 col-groups)
#define A_BUF_BYTES (GM_BM * GM_BK * 2)   // 8192  B per A buffer
#define B_BUF_BYTES (CCH * GM_BK * 2)     // 16384 B per B buffer
#define SCB 2048     // scan elems per block (256 thr x 8)

using f32x4  = __attribute__((ext_vector_type(4))) float;
using bf16x8 = __attribute__((ext_vector_type(8))) short;

__device__ __forceinline__ unsigned short f2bf(float f) {
    union { float f; unsigned u; } v; v.f = f;
    unsigned r = v.u + 0x7FFFu + ((v.u >> 16) & 1u);   // RNE
    return (unsigned short)(r >> 16);
}
__device__ __forceinline__ float bf2f(short h) {
    union { unsigned u; float f; } v;
    v.u = ((unsigned)(unsigned short)h) << 16;
    return v.f;
}
__device__ __forceinline__ void gload16(const void* g, void* l) {
    __builtin_amdgcn_global_load_lds(
        (const __attribute__((address_space(1))) unsigned int*)g,
        (__attribute__((address_space(3))) unsigned int*)l, 16, 0, 0);
}

// ---------------- fp32 -> bf16 convert (both matrices via blockIdx.y) ----------------
__global__ __launch_bounds__(256)
void cvt_bf16(const float* __restrict__ x0, unsigned short* __restrict__ y0,
              const float* __restrict__ x1, unsigned short* __restrict__ y1, long n) {
    const float* x        = blockIdx.y ? x1 : x0;
    unsigned short* y     = blockIdx.y ? y1 : y0;
    long i = ((long)blockIdx.x * 256 + threadIdx.x) * 8;
    if (i >= n) return;
    float4 a = *(const float4*)(x + i);
    float4 b = *(const float4*)(x + i + 4);
    bf16x8 pk;
    pk[0]=(short)f2bf(a.x); pk[1]=(short)f2bf(a.y); pk[2]=(short)f2bf(a.z); pk[3]=(short)f2bf(a.w);
    pk[4]=(short)f2bf(b.x); pk[5]=(short)f2bf(b.y); pk[6]=(short)f2bf(b.z); pk[7]=(short)f2bf(b.w);
    *(bf16x8*)(y + i) = pk;
}

// ------- W concat + bf16: grid.y encodes (dir, layer) -------
__global__ __launch_bounds__(256)
void cvt_wcat(const float* __restrict__ Wl0, const float* __restrict__ Wr0,
              unsigned short* __restrict__ o0,
              const float* __restrict__ Wl1, const float* __restrict__ Wr1,
              unsigned short* __restrict__ o1) {
    const int l   = blockIdx.y & 1;
    const int dir = blockIdx.y >> 1;
    const float* wl = (dir ? Wl1 : Wl0) + (size_t)l * CCH * CCH;
    const float* wr = (dir ? Wr1 : Wr0) + (size_t)l * CCH * CCH;
    unsigned short* o = (dir ? o1 : o0) + (size_t)l * CCH * KTOT;
    int idx = (blockIdx.x * 256 + threadIdx.x) * 8;     // 0..65528
    int col = idx >> 8, k = idx & 255;
    {
        float4 a = *(const float4*)(wl + col * CCH + k);
        float4 b = *(const float4*)(wl + col * CCH + k + 4);
        bf16x8 pk;
        pk[0]=(short)f2bf(a.x); pk[1]=(short)f2bf(a.y); pk[2]=(short)f2bf(a.z); pk[3]=(short)f2bf(a.w);
        pk[4]=(short)f2bf(b.x); pk[5]=(short)f2bf(b.y); pk[6]=(short)f2bf(b.z); pk[7]=(short)f2bf(b.w);
        *(bf16x8*)(o + (size_t)col * KTOT + k) = pk;
    }
    {
        float4 a = *(const float4*)(wr + col * CCH + k);
        float4 b = *(const float4*)(wr + col * CCH + k + 4);
        bf16x8 pk;
        pk[0]=(short)f2bf(a.x); pk[1]=(short)f2bf(a.y); pk[2]=(short)f2bf(a.z); pk[3]=(short)f2bf(a.w);
        pk[4]=(short)f2bf(b.x); pk[5]=(short)f2bf(b.y); pk[6]=(short)f2bf(b.z); pk[7]=(short)f2bf(b.w);
        *(bf16x8*)(o + (size_t)col * KTOT + CCH + k) = pk;
    }
}

// ---------------- CSR build (both directions via blockIdx.y) ----------------
__global__ __launch_bounds__(256)
void hist_kernel(const int* __restrict__ ei0, int* __restrict__ c0,
                 const int* __restrict__ ei1, int* __restrict__ c1, int E) {
    const int* ei = blockIdx.y ? ei1 : ei0;
    int* cnt      = blockIdx.y ? c1  : c0;
    int e = blockIdx.x * blockDim.x + threadIdx.x;
    if (e < E) atomicAdd(&cnt[ei[E + e]], 1);
}

__global__ __launch_bounds__(256)
void scan_part(const int* __restrict__ c0, int* __restrict__ b0,
               const int* __restrict__ c1, int* __restrict__ b1, int N) {
    const int* cnt = blockIdx.y ? c1 : c0;
    int* bsum      = blockIdx.y ? b1 : b0;
    __shared__ int sw[4];
    int t = threadIdx.x;
    int base = blockIdx.x * SCB + t * 8;
    int s = 0;
#pragma unroll
    for (int j = 0; j < 8; ++j) { int idx = base + j; s += (idx < N) ? cnt[idx] : 0; }
    for (int m = 1; m < 64; m <<= 1) s += __shfl_xor(s, m);
    if ((t & 63) == 0) sw[t >> 6] = s;
    __syncthreads();
    if (t == 0) bsum[blockIdx.x] = sw[0] + sw[1] + sw[2] + sw[3];
}

__global__ __launch_bounds__(256)
void scan_bsum(int* __restrict__ ba, int* __restrict__ bb, int nb) {
    int* b = blockIdx.x ? bb : ba;
    __shared__ int s[256];
    int t = threadIdx.x;
    int v = (t < nb) ? b[t] : 0;
    s[t] = v;
    __syncthreads();
    for (int o = 1; o < 256; o <<= 1) {
        int u = 0;
        if (t >= o) u = s[t - o];
        __syncthreads();
        if (t >= o) s[t] += u;
        __syncthreads();
    }
    if (t < nb) b[t] = s[t] - v;   // exclusive
}

__global__ __launch_bounds__(256)
void scan_apply(const int* __restrict__ c0, const int* __restrict__ b0,
                int* __restrict__ r0, int* __restrict__ cur0,
                const int* __restrict__ c1, const int* __restrict__ b1,
                int* __restrict__ r1, int* __restrict__ cur1, int N, int E) {
    const int* cnt  = blockIdx.y ? c1 : c0;
    const int* bsum = blockIdx.y ? b1 : b0;
    int* rowstart   = blockIdx.y ? r1 : r0;
    int* cursor     = blockIdx.y ? cur1 : cur0;
    __shared__ int sw[4];
    int t = threadIdx.x;
    int base = blockIdx.x * SCB + t * 8;
    int v[8]; int s = 0;
#pragma unroll
    for (int j = 0; j < 8; ++j) { int idx = base + j; v[j] = (idx < N) ? cnt[idx] : 0; s += v[j]; }
    int own = s;
    for (int m = 1; m < 64; m <<= 1) {
        int u = __shfl_up(s, m);
        if ((t & 63) >= m) s += u;
    }
    if ((t & 63) == 63) sw[t >> 6] = s;
    __syncthreads();
    int w = t >> 6, woff = 0;
    if (w > 0) woff += sw[0];
    if (w > 1) woff += sw[1];
    if (w > 2) woff += sw[2];
    int excl = bsum[blockIdx.x] + woff + s - own;
#pragma unroll
    for (int j = 0; j < 8; ++j) {
        int idx = base + j;
        if (idx < N) { rowstart[idx] = excl; excl += v[j]; cursor[idx] = 0; }
    }
    if (blockIdx.x == 0 && t == 0) rowstart[N] = E;
}

__global__ __launch_bounds__(256)
void fill_kernel(const int* __restrict__ ei0, const int* __restrict__ r0,
                 int* __restrict__ cur0, int* __restrict__ e0,
                 const int* __restrict__ ei1, const int* __restrict__ r1,
                 int* __restrict__ cur1, int* __restrict__ e1, int E) {
    const int* ei       = blockIdx.y ? ei1 : ei0;
    const int* rowstart = blockIdx.y ? r1  : r0;
    int* cursor         = blockIdx.y ? cur1 : cur0;
    int* elist          = blockIdx.y ? e1  : e0;
    int e = blockIdx.x * blockDim.x + threadIdx.x;
    if (e < E) {
        int dst = ei[E + e];
        int p = atomicAdd(&cursor[dst], 1);
        elist[rowstart[dst] + p] = ei[e];
    }
}

// ------------- gather + mean (bf16), both directions in one dispatch -------------
// FULL wave per node, 2 half-waves process alternating neighbors: serial dependent
// chain drops deg -> ceil(deg/2) and MLP doubles (gather is latency-bound on
// L2/L3-resident rows; avg deg=3). Halves combined via one shfl_xor(32).
__global__ __launch_bounds__(256)
void gather_mean(const unsigned short* __restrict__ xs0, const int* __restrict__ rs0,
                 const int* __restrict__ el0, unsigned short* __restrict__ mn0,
                 const unsigned short* __restrict__ xs1, const int* __restrict__ rs1,
                 const int* __restrict__ el1, unsigned short* __restrict__ mn1, int N) {
    const unsigned short* xsrc = blockIdx.y ? xs1 : xs0;
    const int* rowstart        = blockIdx.y ? rs1 : rs0;
    const int* elist           = blockIdx.y ? el1 : el0;
    unsigned short* mean       = blockIdx.y ? mn1 : mn0;
    int node = (blockIdx.x * blockDim.x + threadIdx.x) >> 6;
    int lane = threadIdx.x & 63;
    int half = lane >> 5;          // 0 or 1
    int ln   = lane & 31;          // 16B chunk within row
    if (node >= N) return;
    int lo = rowstart[node], hi = rowstart[node + 1];
    float a[8] = {0.f,0.f,0.f,0.f,0.f,0.f,0.f,0.f};
    for (int i = lo + half; i < hi; i += 2) {
        int s = elist[i];
        bf16x8 v = *((const bf16x8*)(xsrc + (size_t)s * CCH) + ln);
#pragma unroll
        for (int j = 0; j < 8; ++j) a[j] += bf2f(v[j]);
    }
#pragma unroll
    for (int j = 0; j < 8; ++j) a[j] += __shfl_xor(a[j], 32);   // combine halves
    if (half == 0) {
        float r = (hi > lo) ? 1.0f / (float)(hi - lo) : 0.0f;
        bf16x8 pk;
#pragma unroll
        for (int j = 0; j < 8; ++j) pk[j] = (short)f2bf(a[j] * r);
        *((bf16x8*)(mean + (size_t)node * CCH) + ln) = pk;
    }
}

// ------- fused: h = LNReLU( [mean|xdst] @ Bcat^T + bl ); both directions via blockIdx.y -------
// EXACT r13 structure (proven 148us): 3-deep counted-vmcnt global_load_lds pipeline,
// rule-#18 race fence (lgkmcnt(0)+sched_barrier before counted vmcnt+s_barrier),
// XOR slot swizzle both sides, direct per-wave epilogue stores (r16 lesson: stores
// were already 64B-contiguous; LDS re-staging only added conflicts+barriers).
__global__ __launch_bounds__(GM_TH, 4)
void sage_gemm_ln(const unsigned short* __restrict__ mean0,
                  const unsigned short* __restrict__ xdst0,
                  const unsigned short* __restrict__ Bc0,
                  const float* __restrict__ bl0,
                  const float* __restrict__ gm0, const float* __restrict__ bt0,
                  float* __restrict__ outf0, unsigned short* __restrict__ outb0,
                  const unsigned short* __restrict__ mean1,
                  const unsigned short* __restrict__ xdst1,
                  const unsigned short* __restrict__ Bc1,
                  const float* __restrict__ bl1,
                  const float* __restrict__ gm1, const float* __restrict__ bt1,
                  float* __restrict__ outf1, unsigned short* __restrict__ outb1,
                  int Nrows)
{
    const int dir = blockIdx.y;
    const unsigned short* mean = dir ? mean1 : mean0;
    const unsigned short* xdst = dir ? xdst1 : xdst0;
    const unsigned short* Bcat = dir ? Bc1   : Bc0;
    const float* bl    = dir ? bl1 : bl0;
    const float* gamma = dir ? gm1 : gm0;
    const float* beta  = dir ? bt1 : bt0;
    float* outf          = dir ? outf1 : outf0;
    unsigned short* outb = dir ? outb1 : outb0;

    __shared__ __align__(16) unsigned short As[3 * GM_BM * GM_BK];   // 3 x 8 KB
    __shared__ __align__(16) unsigned short Bs[3 * CCH * GM_BK];     // 3 x 16 KB

    const int tid  = threadIdx.x;
    const int lane = tid & 63;
    const int wr   = tid >> 8;                 // 0..1
    const int wc   = (tid >> 6) & 3;           // 0..3
    const int cl   = lane & 15;
    const int g    = lane >> 4;                // 0..3 -> k-chunk
    const long brow = (long)blockIdx.x * GM_BM;

    f32x4 acc[4][4];
#pragma unroll
    for (int m = 0; m < 4; ++m)
#pragma unroll
        for (int n = 0; n < 4; ++n) acc[m][n] = (f32x4){0.f, 0.f, 0.f, 0.f};

    // per-thread staging coords (constant across steps)
    const int rowA = tid >> 2, slA = tid & 3;               // 1 A-chunk/thread
    long growA = brow + rowA; if (growA > (long)Nrows - 1) growA = (long)Nrows - 1;
    const int swzA = ((slA ^ ((rowA >> 1) & 3)) << 3);
    const int colB0 = tid >> 2,          slB0 = tid & 3;    // 2 B-chunks/thread
    const int colB1 = (tid + 512) >> 2,  slB1 = tid & 3;
    const int swzB0 = ((slB0 ^ ((colB0 >> 1) & 3)) << 3);
    const int swzB1 = ((slB1 ^ ((colB1 >> 1) & 3)) << 3);

#define STAGE(buf, t)                                                              \
    {                                                                              \
        const int kb_ = (t) * GM_BK;                                               \
        const unsigned short* asrc_ = (kb_ < CCH) ? mean : xdst;                   \
        const int akk_ = kb_ & (CCH - 1);                                          \
        gload16(asrc_ + growA * CCH + akk_ + swzA,                                 \
                (char*)As + (buf) * A_BUF_BYTES + tid * 16);                       \
        gload16(Bcat + (size_t)colB0 * KTOT + kb_ + swzB0,                         \
                (char*)Bs + (buf) * B_BUF_BYTES + tid * 16);                       \
        gload16(Bcat + (size_t)colB1 * KTOT + kb_ + swzB1,                         \
                (char*)Bs + (buf) * B_BUF_BYTES + (tid + 512) * 16);               \
    }

    const int nsteps = KTOT / GM_BK;   // 16
    STAGE(0, 0);
    STAGE(1, 1);
    asm volatile("s_waitcnt vmcnt(3)" ::: "memory");   // buf0's 3 loads landed
    __builtin_amdgcn_s_barrier();
    __builtin_amdgcn_sched_barrier(0);
    for (int t = 0; t < nsteps; ++t) {
        if (t + 2 < nsteps) STAGE((t + 2) % 3, t + 2);   // stays in flight across barrier
        const char* Ab = (const char*)As + (t % 3) * A_BUF_BYTES;
        const char* Bb = (const char*)Bs + (t % 3) * B_BUF_BYTES;
        bf16x8 a[4], b[4];
#pragma unroll
        for (int m = 0; m < 4; ++m) {
            int row = wr * 64 + m * 16 + cl;
            int slot = g ^ ((row >> 1) & 3);
            a[m] = *(const bf16x8*)(Ab + row * 64 + slot * 16);
        }
#pragma unroll
        for (int n = 0; n < 4; ++n) {
            int col = wc * 64 + n * 16 + cl;
            int slot = g ^ ((col >> 1) & 3);
            b[n] = *(const bf16x8*)(Bb + col * 64 + slot * 16);
        }
#pragma unroll
        for (int m = 0; m < 4; ++m)
#pragma unroll
            for (int n = 0; n < 4; ++n)
                acc[m][n] = __builtin_amdgcn_mfma_f32_16x16x32_bf16(a[m], b[n], acc[m][n], 0, 0, 0);
        // race fence (rule #18): this wave's ds_reads must have RETURNED before barrier
        asm volatile("s_waitcnt lgkmcnt(0)" ::: "memory");
        __builtin_amdgcn_sched_barrier(0);
        // counted wait: buf(t+1)'s loads retired; buf(t+2)'s may stay in flight
        if (t < nsteps - 2) asm volatile("s_waitcnt vmcnt(3)" ::: "memory");
        else                asm volatile("s_waitcnt vmcnt(0)" ::: "memory");
        __builtin_amdgcn_s_barrier();
        __builtin_amdgcn_sched_barrier(0);
    }
#undef STAGE

    // ---- epilogue: +bias, cross-wave LayerNorm, ReLU, store ----
    float p1[4][4], p2[4][4];   // [m][j]
#pragma unroll
    for (int m = 0; m < 4; ++m)
#pragma unroll
        for (int j = 0; j < 4; ++j) { p1[m][j] = 0.f; p2[m][j] = 0.f; }
#pragma unroll
    for (int n = 0; n < 4; ++n) {
        float bv = bl[wc * 64 + n * 16 + cl];
#pragma unroll
        for (int m = 0; m < 4; ++m)
#pragma unroll
            for (int j = 0; j < 4; ++j) {
                float v = acc[m][n][j] + bv;
                acc[m][n][j] = v;
                p1[m][j] += v;
                p2[m][j] += v * v;
            }
    }
#pragma unroll
    for (int msk = 1; msk < 16; msk <<= 1) {
#pragma unroll
        for (int m = 0; m < 4; ++m)
#pragma unroll
            for (int j = 0; j < 4; ++j) {
                p1[m][j] += __shfl_xor(p1[m][j], msk);
                p2[m][j] += __shfl_xor(p2[m][j], msk);
            }
    }
    float2* red = (float2*)&As[0];   // red[row128][4], 4 KB overlay (post-loop, fully drained)
    if (cl == 0) {
#pragma unroll
        for (int m = 0; m < 4; ++m)
#pragma unroll
            for (int j = 0; j < 4; ++j) {
                int rl = wr * 64 + m * 16 + g * 4 + j;
                red[rl * 4 + wc] = make_float2(p1[m][j], p2[m][j]);
            }
    }
    __syncthreads();

    float gmv[4], btv[4];
#pragma unroll
    for (int n = 0; n < 4; ++n) {
        gmv[n] = gamma[wc * 64 + n * 16 + cl];
        btv[n] = beta[wc * 64 + n * 16 + cl];
    }
#pragma unroll
    for (int m = 0; m < 4; ++m) {
#pragma unroll
        for (int j = 0; j < 4; ++j) {
            int rl = wr * 64 + m * 16 + g * 4 + j;
            f32x4 u0 = *(const f32x4*)&red[rl * 4 + 0];
            f32x4 u1 = *(const f32x4*)&red[rl * 4 + 2];
            float s1 = u0[0] + u0[2] + u1[0] + u1[2];
            float s2 = u0[1] + u0[3] + u1[1] + u1[3];
            float mu = s1 * (1.0f / CCH);
            float var = s2 * (1.0f / CCH) - mu * mu;
            float rsd = rsqrtf(var + 1e-5f);
            long r = brow + rl;
            if (r < Nrows) {
#pragma unroll
                for (int n = 0; n < 4; ++n) {
                    float v = (acc[m][n][j] - mu) * rsd * gmv[n] + btv[n];
                    v = fmaxf(v, 0.f);
                    long off = r * CCH + wc * 64 + n * 16 + cl;
                    if (outf) outf[off] = v;
                    if (outb) outb[off] = f2bf(v);
                }
            }
        }
    }
}

extern "C" void kernel_launch(void* const* d_in, const int* in_sizes, int n_in,
                              void* d_out, int out_size, void* d_ws, size_t ws_size,
                              hipStream_t stream) {
    const float* x_user = (const float*)d_in[0];
    const float* x_item = (const float*)d_in[1];
    const int*   ei_u2i = (const int*)d_in[2];
    const int*   ei_i2u = (const int*)d_in[3];
    const float* Wl_u2i = (const float*)d_in[4];
    const float* bl_u2i = (const float*)d_in[5];
    const float* Wr_u2i = (const float*)d_in[6];
    const float* Wl_i2u = (const float*)d_in[7];
    const float* bl_i2u = (const float*)d_in[8];
    const float* Wr_i2u = (const float*)d_in[9];
    const float* g_user = (const float*)d_in[10];
    const float* b_user = (const float*)d_in[11];
    const float* g_item = (const float*)d_in[12];
    const float* b_item = (const float*)d_in[13];

    const int N = in_sizes[0] / CCH;
    const int E = in_sizes[2] / 2;
    const size_t NC = (size_t)N * CCH;
    const int nb = (N + SCB - 1) / SCB;

    // workspace layout (~210 MB)
    char* p = (char*)d_ws;
    unsigned short* xb_u   = (unsigned short*)p; p += NC * sizeof(unsigned short);
    unsigned short* xb_i   = (unsigned short*)p; p += NC * sizeof(unsigned short);
    unsigned short* mean_i = (unsigned short*)p; p += NC * sizeof(unsigned short);
    unsigned short* mean_u = (unsigned short*)p; p += NC * sizeof(unsigned short);
    unsigned short* wc_u2i = (unsigned short*)p; p += (size_t)2 * CCH * KTOT * sizeof(unsigned short);
    unsigned short* wc_i2u = (unsigned short*)p; p += (size_t)2 * CCH * KTOT * sizeof(unsigned short);
    int* cnt_i  = (int*)p; p += (size_t)N * sizeof(int);   // doubles as fill cursor
    int* cnt_u  = (int*)p; p += (size_t)N * sizeof(int);   // contiguous with cnt_i (one memset)
    int* rs_i   = (int*)p; p += (size_t)(N + 1) * sizeof(int);
    int* rs_u   = (int*)p; p += (size_t)(N + 1) * sizeof(int);
    int* el_i   = (int*)p; p += (size_t)E * sizeof(int);
    int* el_u   = (int*)p; p += (size_t)E * sizeof(int);
    int* bs_i   = (int*)p; p += 256 * sizeof(int);
    int* bs_u   = (int*)p; p += 256 * sizeof(int);

    float* out_user = (float*)d_out;
    float* out_item = out_user + NC;

    const int eb = (E + 255) / 256;
    const int cb = (int)((NC / 8 + 255) / 256);
    const int gm_blocks = (N + GM_BM - 1) / GM_BM;
    const int gw_blocks = (int)(((size_t)N * 64 + 255) / 256);   // full wave per node

    // ---- CSR build (merged: one dispatch per pass) ----
    hipMemsetAsync(cnt_i, 0, (size_t)2 * N * sizeof(int), stream);   // cnt_i + cnt_u
    hist_kernel<<<dim3(eb, 2), 256, 0, stream>>>(ei_u2i, cnt_i, ei_i2u, cnt_u, E);
    scan_part<<<dim3(nb, 2), 256, 0, stream>>>(cnt_i, bs_i, cnt_u, bs_u, N);
    scan_bsum<<<2, 256, 0, stream>>>(bs_i, bs_u, nb);
    scan_apply<<<dim3(nb, 2), 256, 0, stream>>>(cnt_i, bs_i, rs_i, cnt_i,
                                                cnt_u, bs_u, rs_u, cnt_u, N, E);
    fill_kernel<<<dim3(eb, 2), 256, 0, stream>>>(ei_u2i, rs_i, cnt_i, el_i,
                                                 ei_i2u, rs_u, cnt_u, el_u, E);

    // ---- weight concat + bf16 (once) ----
    cvt_wcat<<<dim3(32, 4), 256, 0, stream>>>(Wl_u2i, Wr_u2i, wc_u2i,
                                              Wl_i2u, Wr_i2u, wc_i2u);

    // ---- bf16 copies of inputs ----
    cvt_bf16<<<dim3(cb, 2), 256, 0, stream>>>(x_user, xb_u, x_item, xb_i, (long)NC);

    for (int l = 0; l < 2; ++l) {
        const size_t wl = (size_t)l * CCH * KTOT;
        gather_mean<<<dim3(gw_blocks, 2), 256, 0, stream>>>(
            xb_u, rs_i, el_i, mean_i,
            xb_i, rs_u, el_u, mean_u, N);
        if (l == 0) {
            sage_gemm_ln<<<dim3(gm_blocks, 2), GM_TH, 0, stream>>>(
                mean_i, xb_i, wc_u2i + wl, bl_u2i + l * CCH, g_item + l * CCH, b_item + l * CCH,
                nullptr, xb_i,
                mean_u, xb_u, wc_i2u + wl, bl_i2u + l * CCH, g_user + l * CCH, b_user + l * CCH,
                nullptr, xb_u, N);
        } else {
            sage_gemm_ln<<<dim3(gm_blocks, 2), GM_TH, 0, stream>>>(
                mean_i, xb_i, wc_u2i + wl, bl_u2i + l * CCH, g_item + l * CCH, b_item + l * CCH,
                out_item, nullptr,
                mean_u, xb_u, wc_i2u + wl, bl_i2u + l * CCH, g_user + l * CCH, b_user + l * CCH,
                out_user, nullptr, N);
        }
    }
}

// Round 18
// 512.671 us; speedup vs baseline: 1.1433x; 1.0620x over previous
//
#include <hip/hip_runtime.h>

#define CCH 256      // channels
#define KTOT 512     // mean(256) ++ x_dst(256)
#define GM_BM 64     // rows per block (fused kernel)
#define GM_BK 32     // K-step
#define GM_TH 512    // threads (8 waves: 2 row x 4 col)
#define AME_BYTES (GM_BM * CCH * 2)       // 32768 B: A tile (mean, then xdst)
#define B_BUF_BYTES (CCH * GM_BK * 2)     // 16384 B per B buffer
#define SCB 2048

using f32x4  = __attribute__((ext_vector_type(4))) float;
using bf16x8 = __attribute__((ext_vector_type(8))) short;

__device__ __forceinline__ unsigned short f2bf(float f) {
    union { float f; unsigned u; } v; v.f = f;
    unsigned r = v.u + 0x7FFFu + ((v.u >> 16) & 1u);   // RNE
    return (unsigned short)(r >> 16);
}
__device__ __forceinline__ float bf2f(short h) {
    union { unsigned u; float f; } v;
    v.u = ((unsigned)(unsigned short)h) << 16;
    return v.f;
}
__device__ __forceinline__ void gload16(const void* g, void* l) {
    __builtin_amdgcn_global_load_lds(
        (const __attribute__((address_space(1))) unsigned int*)g,
        (__attribute__((address_space(3))) unsigned int*)l, 16, 0, 0);
}

// ---------------- fp32 -> bf16 convert (both matrices via blockIdx.y) ----------------
__global__ __launch_bounds__(256)
void cvt_bf16(const float* __restrict__ x0, unsigned short* __restrict__ y0,
              const float* __restrict__ x1, unsigned short* __restrict__ y1, long n) {
    const float* x        = blockIdx.y ? x1 : x0;
    unsigned short* y     = blockIdx.y ? y1 : y0;
    long i = ((long)blockIdx.x * 256 + threadIdx.x) * 8;
    if (i >= n) return;
    float4 a = *(const float4*)(x + i);
    float4 b = *(const float4*)(x + i + 4);
    bf16x8 pk;
    pk[0]=(short)f2bf(a.x); pk[1]=(short)f2bf(a.y); pk[2]=(short)f2bf(a.z); pk[3]=(short)f2bf(a.w);
    pk[4]=(short)f2bf(b.x); pk[5]=(short)f2bf(b.y); pk[6]=(short)f2bf(b.z); pk[7]=(short)f2bf(b.w);
    *(bf16x8*)(y + i) = pk;
}

// ------- W concat + bf16: grid.y encodes (dir, layer) -------
__global__ __launch_bounds__(256)
void cvt_wcat(const float* __restrict__ Wl0, const float* __restrict__ Wr0,
              unsigned short* __restrict__ o0,
              const float* __restrict__ Wl1, const float* __restrict__ Wr1,
              unsigned short* __restrict__ o1) {
    const int l   = blockIdx.y & 1;
    const int dir = blockIdx.y >> 1;
    const float* wl = (dir ? Wl1 : Wl0) + (size_t)l * CCH * CCH;
    const float* wr = (dir ? Wr1 : Wr0) + (size_t)l * CCH * CCH;
    unsigned short* o = (dir ? o1 : o0) + (size_t)l * CCH * KTOT;
    int idx = (blockIdx.x * 256 + threadIdx.x) * 8;
    int col = idx >> 8, k = idx & 255;
    {
        float4 a = *(const float4*)(wl + col * CCH + k);
        float4 b = *(const float4*)(wl + col * CCH + k + 4);
        bf16x8 pk;
        pk[0]=(short)f2bf(a.x); pk[1]=(short)f2bf(a.y); pk[2]=(short)f2bf(a.z); pk[3]=(short)f2bf(a.w);
        pk[4]=(short)f2bf(b.x); pk[5]=(short)f2bf(b.y); pk[6]=(short)f2bf(b.z); pk[7]=(short)f2bf(b.w);
        *(bf16x8*)(o + (size_t)col * KTOT + k) = pk;
    }
    {
        float4 a = *(const float4*)(wr + col * CCH + k);
        float4 b = *(const float4*)(wr + col * CCH + k + 4);
        bf16x8 pk;
        pk[0]=(short)f2bf(a.x); pk[1]=(short)f2bf(a.y); pk[2]=(short)f2bf(a.z); pk[3]=(short)f2bf(a.w);
        pk[4]=(short)f2bf(b.x); pk[5]=(short)f2bf(b.y); pk[6]=(short)f2bf(b.z); pk[7]=(short)f2bf(b.w);
        *(bf16x8*)(o + (size_t)col * KTOT + CCH + k) = pk;
    }
}

// ---------------- CSR build (both directions via blockIdx.y) ----------------
__global__ __launch_bounds__(256)
void hist_kernel(const int* __restrict__ ei0, int* __restrict__ c0,
                 const int* __restrict__ ei1, int* __restrict__ c1, int E) {
    const int* ei = blockIdx.y ? ei1 : ei0;
    int* cnt      = blockIdx.y ? c1  : c0;
    int e = blockIdx.x * blockDim.x + threadIdx.x;
    if (e < E) atomicAdd(&cnt[ei[E + e]], 1);
}

__global__ __launch_bounds__(256)
void scan_part(const int* __restrict__ c0, int* __restrict__ b0,
               const int* __restrict__ c1, int* __restrict__ b1, int N) {
    const int* cnt = blockIdx.y ? c1 : c0;
    int* bsum      = blockIdx.y ? b1 : b0;
    __shared__ int sw[4];
    int t = threadIdx.x;
    int base = blockIdx.x * SCB + t * 8;
    int s = 0;
#pragma unroll
    for (int j = 0; j < 8; ++j) { int idx = base + j; s += (idx < N) ? cnt[idx] : 0; }
    for (int m = 1; m < 64; m <<= 1) s += __shfl_xor(s, m);
    if ((t & 63) == 0) sw[t >> 6] = s;
    __syncthreads();
    if (t == 0) bsum[blockIdx.x] = sw[0] + sw[1] + sw[2] + sw[3];
}

__global__ __launch_bounds__(256)
void scan_bsum(int* __restrict__ ba, int* __restrict__ bb, int nb) {
    int* b = blockIdx.x ? bb : ba;
    __shared__ int s[256];
    int t = threadIdx.x;
    int v = (t < nb) ? b[t] : 0;
    s[t] = v;
    __syncthreads();
    for (int o = 1; o < 256; o <<= 1) {
        int u = 0;
        if (t >= o) u = s[t - o];
        __syncthreads();
        if (t >= o) s[t] += u;
        __syncthreads();
    }
    if (t < nb) b[t] = s[t] - v;   // exclusive
}

__global__ __launch_bounds__(256)
void scan_apply(const int* __restrict__ c0, const int* __restrict__ b0,
                int* __restrict__ r0, int* __restrict__ cur0,
                const int* __restrict__ c1, const int* __restrict__ b1,
                int* __restrict__ r1, int* __restrict__ cur1, int N, int E) {
    const int* cnt  = blockIdx.y ? c1 : c0;
    const int* bsum = blockIdx.y ? b1 : b0;
    int* rowstart   = blockIdx.y ? r1 : r0;
    int* cursor     = blockIdx.y ? cur1 : cur0;
    __shared__ int sw[4];
    int t = threadIdx.x;
    int base = blockIdx.x * SCB + t * 8;
    int v[8]; int s = 0;
#pragma unroll
    for (int j = 0; j < 8; ++j) { int idx = base + j; v[j] = (idx < N) ? cnt[idx] : 0; s += v[j]; }
    int own = s;
    for (int m = 1; m < 64; m <<= 1) {
        int u = __shfl_up(s, m);
        if ((t & 63) >= m) s += u;
    }
    if ((t & 63) == 63) sw[t >> 6] = s;
    __syncthreads();
    int w = t >> 6, woff = 0;
    if (w > 0) woff += sw[0];
    if (w > 1) woff += sw[1];
    if (w > 2) woff += sw[2];
    int excl = bsum[blockIdx.x] + woff + s - own;
#pragma unroll
    for (int j = 0; j < 8; ++j) {
        int idx = base + j;
        if (idx < N) { rowstart[idx] = excl; excl += v[j]; cursor[idx] = 0; }
    }
    if (blockIdx.x == 0 && t == 0) rowstart[N] = E;
}

__global__ __launch_bounds__(256)
void fill_kernel(const int* __restrict__ ei0, const int* __restrict__ r0,
                 int* __restrict__ cur0, int* __restrict__ e0,
                 const int* __restrict__ ei1, const int* __restrict__ r1,
                 int* __restrict__ cur1, int* __restrict__ e1, int E) {
    const int* ei       = blockIdx.y ? ei1 : ei0;
    const int* rowstart = blockIdx.y ? r1  : r0;
    int* cursor         = blockIdx.y ? cur1 : cur0;
    int* elist          = blockIdx.y ? e1  : e0;
    int e = blockIdx.x * blockDim.x + threadIdx.x;
    if (e < E) {
        int dst = ei[E + e];
        int p = atomicAdd(&cursor[dst], 1);
        elist[rowstart[dst] + p] = ei[e];
    }
}

// ======= FUSED: gather-mean (into LDS) + GEMM + LN + ReLU; dirs via blockIdx.y =======
// Phase 1: 16 half-waves gather the block's 64 mean rows -> Ame (bf16, XOR-swz slots).
// Phase 2: K-steps 0-7 read A from Ame; B via r13-proven 3-deep counted-vmcnt pipeline.
// Phase 3: at t==8 (Ame dead after t=7 barrier) re-stage Ame with xdst rows via linear-
//          dest gload16 (rule 21: per-lane swizzle on SOURCE), one-off vmcnt(2)+barrier.
// LDS = 32KB Ame + 3x16KB B = 80KB exact -> 2 blocks/CU.
__global__ __launch_bounds__(GM_TH, 4)
void sage_fused(const unsigned short* __restrict__ xg0, const int* __restrict__ rs0,
                const int* __restrict__ el0, const unsigned short* __restrict__ xd0,
                const unsigned short* __restrict__ Bc0, const float* __restrict__ bl0,
                const float* __restrict__ gm0, const float* __restrict__ bt0,
                float* __restrict__ outf0, unsigned short* __restrict__ outb0,
                const unsigned short* __restrict__ xg1, const int* __restrict__ rs1,
                const int* __restrict__ el1, const unsigned short* __restrict__ xd1,
                const unsigned short* __restrict__ Bc1, const float* __restrict__ bl1,
                const float* __restrict__ gm1, const float* __restrict__ bt1,
                float* __restrict__ outf1, unsigned short* __restrict__ outb1,
                int Nrows)
{
    const int dir = blockIdx.y;
    const unsigned short* xg   = dir ? xg1 : xg0;   // gather source (other type)
    const int* rowstart        = dir ? rs1 : rs0;
    const int* elist           = dir ? el1 : el0;
    const unsigned short* xd   = dir ? xd1 : xd0;   // self features
    const unsigned short* Bcat = dir ? Bc1 : Bc0;
    const float* bl    = dir ? bl1 : bl0;
    const float* gamma = dir ? gm1 : gm0;
    const float* beta  = dir ? bt1 : bt0;
    float* outf          = dir ? outf1 : outf0;
    unsigned short* outb = dir ? outb1 : outb0;

    __shared__ __align__(16) char smem[AME_BYTES + 3 * B_BUF_BYTES];   // 80 KB
    unsigned short* Ame = (unsigned short*)smem;     // [64][256] bf16, swz slots
    char* Bsb = smem + AME_BYTES;

    const int tid  = threadIdx.x;
    const int lane = tid & 63;
    const int wr   = tid >> 8;                 // 0..1 (32-row groups)
    const int wc   = (tid >> 6) & 3;           // 0..3 (64-col groups)
    const int cl   = lane & 15;
    const int g    = lane >> 4;                // 0..3 -> k-chunk
    const long brow = (long)blockIdx.x * GM_BM;

    // B staging coords (r13 verbatim)
    const int colB0 = tid >> 2,          slB0 = tid & 3;
    const int colB1 = (tid + 512) >> 2,  slB1 = tid & 3;
    const int swzB0 = ((slB0 ^ ((colB0 >> 1) & 3)) << 3);
    const int swzB1 = ((slB1 ^ ((colB1 >> 1) & 3)) << 3);

#define STAGE_B(buf, t_)                                                           \
    {                                                                              \
        const int kb_ = (t_) * GM_BK;                                              \
        gload16(Bcat + (size_t)colB0 * KTOT + kb_ + swzB0,                         \
                Bsb + (buf) * B_BUF_BYTES + tid * 16);                             \
        gload16(Bcat + (size_t)colB1 * KTOT + kb_ + swzB1,                         \
                Bsb + (buf) * B_BUF_BYTES + (tid + 512) * 16);                     \
    }

    STAGE_B(0, 0);
    STAGE_B(1, 1);

    // ---- phase 1: gather mean rows into Ame (half-wave per row, 4 rounds) ----
    const int hw = tid >> 5;       // 0..15
    const int ln = tid & 31;       // 16B chunk within row
    for (int r8 = 0; r8 < 4; ++r8) {
        int row = hw + r8 * 16;
        long grow = brow + row; if (grow > (long)Nrows - 1) grow = (long)Nrows - 1;
        int lo = rowstart[grow], hi = rowstart[grow + 1];
        float a[8] = {0.f,0.f,0.f,0.f,0.f,0.f,0.f,0.f};
        for (int i = lo; i < hi; ++i) {
            int s = elist[i];
            bf16x8 v = *((const bf16x8*)(xg + (size_t)s * CCH) + ln);
#pragma unroll
            for (int j = 0; j < 8; ++j) a[j] += bf2f(v[j]);
        }
        float rr = (hi > lo) ? 1.0f / (float)(hi - lo) : 0.0f;
        bf16x8 pk;
#pragma unroll
        for (int j = 0; j < 8; ++j) pk[j] = (short)f2bf(a[j] * rr);
        *(bf16x8*)&Ame[row * CCH + ((ln ^ (row & 7)) << 3)] = pk;
    }
    __syncthreads();   // Ame ready; drains B0/B1 too (fine)

    f32x4 acc[2][4];
#pragma unroll
    for (int m = 0; m < 2; ++m)
#pragma unroll
        for (int n = 0; n < 4; ++n) acc[m][n] = (f32x4){0.f, 0.f, 0.f, 0.f};

    for (int t = 0; t < 16; ++t) {
        if (t == 8) {
            // Ame dead (t=7's end barrier passed) -> restage with xdst rows.
            // Dest = wave-uniform + lane*16 (legal); swizzle on per-lane SOURCE:
            // slot s of row r holds global chunk s^(r&7); r&7 == hw&7.
#pragma unroll
            for (int j = 0; j < 4; ++j) {
                int row = hw + j * 16;
                long grow = brow + row; if (grow > (long)Nrows - 1) grow = (long)Nrows - 1;
                gload16(xd + grow * CCH + ((ln ^ (hw & 7)) << 3),
                        (char*)Ame + (size_t)(row * 32 + ln) * 16);
            }
            STAGE_B(1, 10);   // 10 % 3 == 1
            asm volatile("s_waitcnt vmcnt(2)" ::: "memory");   // B9 + A landed; B10 in flight
            __builtin_amdgcn_s_barrier();
            __builtin_amdgcn_sched_barrier(0);
        } else if (t + 2 < 16) {
            STAGE_B((t + 2) % 3, t + 2);
        }
        const char* Bb = Bsb + (t % 3) * B_BUF_BYTES;
        const int ct = (t & 7) * 4 + g;            // chunk within 256-elem A row
        bf16x8 a[2], b[4];
#pragma unroll
        for (int m = 0; m < 2; ++m) {
            int row = wr * 32 + m * 16 + cl;
            int slot = ct ^ (cl & 7);
            a[m] = *(const bf16x8*)&Ame[row * CCH + slot * 8];
        }
#pragma unroll
        for (int n = 0; n < 4; ++n) {
            int col = wc * 64 + n * 16 + cl;
            int slot = g ^ ((col >> 1) & 3);
            b[n] = *(const bf16x8*)(Bb + col * 64 + slot * 16);
        }
#pragma unroll
        for (int m = 0; m < 2; ++m)
#pragma unroll
            for (int n = 0; n < 4; ++n)
                acc[m][n] = __builtin_amdgcn_mfma_f32_16x16x32_bf16(a[m], b[n], acc[m][n], 0, 0, 0);
        // race fence (rule #18): ds_reads returned before barrier
        asm volatile("s_waitcnt lgkmcnt(0)" ::: "memory");
        __builtin_amdgcn_sched_barrier(0);
        if (t < 13) asm volatile("s_waitcnt vmcnt(2)" ::: "memory");
        else        asm volatile("s_waitcnt vmcnt(0)" ::: "memory");
        __builtin_amdgcn_s_barrier();
        __builtin_amdgcn_sched_barrier(0);
    }
#undef STAGE_B

    // ---- epilogue: +bias, cross-wave LayerNorm, ReLU, store ----
    float p1[2][4], p2[2][4];
#pragma unroll
    for (int m = 0; m < 2; ++m)
#pragma unroll
        for (int j = 0; j < 4; ++j) { p1[m][j] = 0.f; p2[m][j] = 0.f; }
#pragma unroll
    for (int n = 0; n < 4; ++n) {
        float bv = bl[wc * 64 + n * 16 + cl];
#pragma unroll
        for (int m = 0; m < 2; ++m)
#pragma unroll
            for (int j = 0; j < 4; ++j) {
                float v = acc[m][n][j] + bv;
                acc[m][n][j] = v;
                p1[m][j] += v;
                p2[m][j] += v * v;
            }
    }
#pragma unroll
    for (int msk = 1; msk < 16; msk <<= 1) {
#pragma unroll
        for (int m = 0; m < 2; ++m)
#pragma unroll
            for (int j = 0; j < 4; ++j) {
                p1[m][j] += __shfl_xor(p1[m][j], msk);
                p2[m][j] += __shfl_xor(p2[m][j], msk);
            }
    }
    float2* red = (float2*)smem;   // red[64][4], 2 KB overlay (fully drained)
    if (cl == 0) {
#pragma unroll
        for (int m = 0; m < 2; ++m)
#pragma unroll
            for (int j = 0; j < 4; ++j) {
                int rl = wr * 32 + m * 16 + g * 4 + j;
                red[rl * 4 + wc] = make_float2(p1[m][j], p2[m][j]);
            }
    }
    __syncthreads();

    float gmv[4], btv[4];
#pragma unroll
    for (int n = 0; n < 4; ++n) {
        gmv[n] = gamma[wc * 64 + n * 16 + cl];
        btv[n] = beta[wc * 64 + n * 16 + cl];
    }
#pragma unroll
    for (int m = 0; m < 2; ++m) {
#pragma unroll
        for (int j = 0; j < 4; ++j) {
            int rl = wr * 32 + m * 16 + g * 4 + j;
            f32x4 u0 = *(const f32x4*)&red[rl * 4 + 0];
            f32x4 u1 = *(const f32x4*)&red[rl * 4 + 2];
            float s1 = u0[0] + u0[2] + u1[0] + u1[2];
            float s2 = u0[1] + u0[3] + u1[1] + u1[3];
            float mu = s1 * (1.0f / CCH);
            float var = s2 * (1.0f / CCH) - mu * mu;
            float rsd = rsqrtf(var + 1e-5f);
            long r = brow + rl;
            if (r < Nrows) {
#pragma unroll
                for (int n = 0; n < 4; ++n) {
                    float v = (acc[m][n][j] - mu) * rsd * gmv[n] + btv[n];
                    v = fmaxf(v, 0.f);
                    long off = r * CCH + wc * 64 + n * 16 + cl;
                    if (outf) outf[off] = v;
                    if (outb) outb[off] = f2bf(v);
                }
            }
        }
    }
}

extern "C" void kernel_launch(void* const* d_in, const int* in_sizes, int n_in,
                              void* d_out, int out_size, void* d_ws, size_t ws_size,
                              hipStream_t stream) {
    const float* x_user = (const float*)d_in[0];
    const float* x_item = (const float*)d_in[1];
    const int*   ei_u2i = (const int*)d_in[2];
    const int*   ei_i2u = (const int*)d_in[3];
    const float* Wl_u2i = (const float*)d_in[4];
    const float* bl_u2i = (const float*)d_in[5];
    const float* Wr_u2i = (const float*)d_in[6];
    const float* Wl_i2u = (const float*)d_in[7];
    const float* bl_i2u = (const float*)d_in[8];
    const float* Wr_i2u = (const float*)d_in[9];
    const float* g_user = (const float*)d_in[10];
    const float* b_user = (const float*)d_in[11];
    const float* g_item = (const float*)d_in[12];
    const float* b_item = (const float*)d_in[13];

    const int N = in_sizes[0] / CCH;
    const int E = in_sizes[2] / 2;
    const size_t NC = (size_t)N * CCH;
    const int nb = (N + SCB - 1) / SCB;

    // workspace layout (~210 MB)
    char* p = (char*)d_ws;
    unsigned short* xb_u = (unsigned short*)p; p += NC * sizeof(unsigned short);   // layer-1 input
    unsigned short* xb_i = (unsigned short*)p; p += NC * sizeof(unsigned short);
    unsigned short* xo_u = (unsigned short*)p; p += NC * sizeof(unsigned short);   // layer-1 output
    unsigned short* xo_i = (unsigned short*)p; p += NC * sizeof(unsigned short);
    unsigned short* wc_u2i = (unsigned short*)p; p += (size_t)2 * CCH * KTOT * sizeof(unsigned short);
    unsigned short* wc_i2u = (unsigned short*)p; p += (size_t)2 * CCH * KTOT * sizeof(unsigned short);
    int* cnt_i  = (int*)p; p += (size_t)N * sizeof(int);   // doubles as fill cursor
    int* cnt_u  = (int*)p; p += (size_t)N * sizeof(int);
    int* rs_i   = (int*)p; p += (size_t)(N + 1) * sizeof(int);
    int* rs_u   = (int*)p; p += (size_t)(N + 1) * sizeof(int);
    int* el_i   = (int*)p; p += (size_t)E * sizeof(int);
    int* el_u   = (int*)p; p += (size_t)E * sizeof(int);
    int* bs_i   = (int*)p; p += 256 * sizeof(int);
    int* bs_u   = (int*)p; p += 256 * sizeof(int);

    float* out_user = (float*)d_out;
    float* out_item = out_user + NC;

    const int eb = (E + 255) / 256;
    const int cb = (int)((NC / 8 + 255) / 256);
    const int gm_blocks = (N + GM_BM - 1) / GM_BM;

    // ---- CSR build ----
    hipMemsetAsync(cnt_i, 0, (size_t)2 * N * sizeof(int), stream);
    hist_kernel<<<dim3(eb, 2), 256, 0, stream>>>(ei_u2i, cnt_i, ei_i2u, cnt_u, E);
    scan_part<<<dim3(nb, 2), 256, 0, stream>>>(cnt_i, bs_i, cnt_u, bs_u, N);
    scan_bsum<<<2, 256, 0, stream>>>(bs_i, bs_u, nb);
    scan_apply<<<dim3(nb, 2), 256, 0, stream>>>(cnt_i, bs_i, rs_i, cnt_i,
                                                cnt_u, bs_u, rs_u, cnt_u, N, E);
    fill_kernel<<<dim3(eb, 2), 256, 0, stream>>>(ei_u2i, rs_i, cnt_i, el_i,
                                                 ei_i2u, rs_u, cnt_u, el_u, E);

    // ---- weight concat + bf16 ----
    cvt_wcat<<<dim3(32, 4), 256, 0, stream>>>(Wl_u2i, Wr_u2i, wc_u2i,
                                              Wl_i2u, Wr_i2u, wc_i2u);

    // ---- bf16 copies of inputs ----
    cvt_bf16<<<dim3(cb, 2), 256, 0, stream>>>(x_user, xb_u, x_item, xb_i, (long)NC);

    // ---- layer 1: reads xb_*, writes xo_* (bf16) ----
    sage_fused<<<dim3(gm_blocks, 2), GM_TH, 0, stream>>>(
        xb_u, rs_i, el_i, xb_i, wc_u2i, bl_u2i, g_item, b_item, nullptr, xo_i,
        xb_i, rs_u, el_u, xb_u, wc_i2u, bl_i2u, g_user, b_user, nullptr, xo_u, N);

    // ---- layer 2: reads xo_*, writes d_out (fp32) ----
    sage_fused<<<dim3(gm_blocks, 2), GM_TH, 0, stream>>>(
        xo_u, rs_i, el_i, xo_i, wc_u2i + (size_t)CCH * KTOT, bl_u2i + CCH,
        g_item + CCH, b_item + CCH, out_item, nullptr,
        xo_i, rs_u, el_u, xo_u, wc_i2u + (size_t)CCH * KTOT, bl_i2u + CCH,
        g_user + CCH, b_user + CCH, out_user, nullptr, N);
}

// Round 19
// 511.257 us; speedup vs baseline: 1.1465x; 1.0028x over previous
//
#include <hip/hip_runtime.h>

#define CCH 256      // channels
#define KTOT 512     // mean(256) ++ x_dst(256)
#define GM_BM 64     // rows per block (fused kernel)
#define GM_BK 32     // K-step
#define GM_TH 512    // threads (8 waves: 2 row x 4 col)
#define AME_BYTES (GM_BM * CCH * 2)       // 32768 B: A tile (mean, then xdst)
#define B_BUF_BYTES (CCH * GM_BK * 2)     // 16384 B per B buffer
#define SCB 2048

using f32x4  = __attribute__((ext_vector_type(4))) float;
using bf16x8 = __attribute__((ext_vector_type(8))) short;

__device__ __forceinline__ unsigned short f2bf(float f) {
    union { float f; unsigned u; } v; v.f = f;
    unsigned r = v.u + 0x7FFFu + ((v.u >> 16) & 1u);   // RNE
    return (unsigned short)(r >> 16);
}
__device__ __forceinline__ float bf2f(short h) {
    union { unsigned u; float f; } v;
    v.u = ((unsigned)(unsigned short)h) << 16;
    return v.f;
}
__device__ __forceinline__ void gload16(const void* g, void* l) {
    __builtin_amdgcn_global_load_lds(
        (const __attribute__((address_space(1))) unsigned int*)g,
        (__attribute__((address_space(3))) unsigned int*)l, 16, 0, 0);
}

// ---------------- fp32 -> bf16 convert (both matrices via blockIdx.y) ----------------
__global__ __launch_bounds__(256)
void cvt_bf16(const float* __restrict__ x0, unsigned short* __restrict__ y0,
              const float* __restrict__ x1, unsigned short* __restrict__ y1, long n) {
    const float* x        = blockIdx.y ? x1 : x0;
    unsigned short* y     = blockIdx.y ? y1 : y0;
    long i = ((long)blockIdx.x * 256 + threadIdx.x) * 8;
    if (i >= n) return;
    float4 a = *(const float4*)(x + i);
    float4 b = *(const float4*)(x + i + 4);
    bf16x8 pk;
    pk[0]=(short)f2bf(a.x); pk[1]=(short)f2bf(a.y); pk[2]=(short)f2bf(a.z); pk[3]=(short)f2bf(a.w);
    pk[4]=(short)f2bf(b.x); pk[5]=(short)f2bf(b.y); pk[6]=(short)f2bf(b.z); pk[7]=(short)f2bf(b.w);
    *(bf16x8*)(y + i) = pk;
}

// ------- W concat + bf16: grid.y encodes (dir, layer) -------
__global__ __launch_bounds__(256)
void cvt_wcat(const float* __restrict__ Wl0, const float* __restrict__ Wr0,
              unsigned short* __restrict__ o0,
              const float* __restrict__ Wl1, const float* __restrict__ Wr1,
              unsigned short* __restrict__ o1) {
    const int l   = blockIdx.y & 1;
    const int dir = blockIdx.y >> 1;
    const float* wl = (dir ? Wl1 : Wl0) + (size_t)l * CCH * CCH;
    const float* wr = (dir ? Wr1 : Wr0) + (size_t)l * CCH * CCH;
    unsigned short* o = (dir ? o1 : o0) + (size_t)l * CCH * KTOT;
    int idx = (blockIdx.x * 256 + threadIdx.x) * 8;
    int col = idx >> 8, k = idx & 255;
    {
        float4 a = *(const float4*)(wl + col * CCH + k);
        float4 b = *(const float4*)(wl + col * CCH + k + 4);
        bf16x8 pk;
        pk[0]=(short)f2bf(a.x); pk[1]=(short)f2bf(a.y); pk[2]=(short)f2bf(a.z); pk[3]=(short)f2bf(a.w);
        pk[4]=(short)f2bf(b.x); pk[5]=(short)f2bf(b.y); pk[6]=(short)f2bf(b.z); pk[7]=(short)f2bf(b.w);
        *(bf16x8*)(o + (size_t)col * KTOT + k) = pk;
    }
    {
        float4 a = *(const float4*)(wr + col * CCH + k);
        float4 b = *(const float4*)(wr + col * CCH + k + 4);
        bf16x8 pk;
        pk[0]=(short)f2bf(a.x); pk[1]=(short)f2bf(a.y); pk[2]=(short)f2bf(a.z); pk[3]=(short)f2bf(a.w);
        pk[4]=(short)f2bf(b.x); pk[5]=(short)f2bf(b.y); pk[6]=(short)f2bf(b.z); pk[7]=(short)f2bf(b.w);
        *(bf16x8*)(o + (size_t)col * KTOT + CCH + k) = pk;
    }
}

// ---------------- CSR build (both directions via blockIdx.y) ----------------
__global__ __launch_bounds__(256)
void hist_kernel(const int* __restrict__ ei0, int* __restrict__ c0,
                 const int* __restrict__ ei1, int* __restrict__ c1, int E) {
    const int* ei = blockIdx.y ? ei1 : ei0;
    int* cnt      = blockIdx.y ? c1  : c0;
    int e = blockIdx.x * blockDim.x + threadIdx.x;
    if (e < E) atomicAdd(&cnt[ei[E + e]], 1);
}

__global__ __launch_bounds__(256)
void scan_part(const int* __restrict__ c0, int* __restrict__ b0,
               const int* __restrict__ c1, int* __restrict__ b1, int N) {
    const int* cnt = blockIdx.y ? c1 : c0;
    int* bsum      = blockIdx.y ? b1 : b0;
    __shared__ int sw[4];
    int t = threadIdx.x;
    int base = blockIdx.x * SCB + t * 8;
    int s = 0;
#pragma unroll
    for (int j = 0; j < 8; ++j) { int idx = base + j; s += (idx < N) ? cnt[idx] : 0; }
    for (int m = 1; m < 64; m <<= 1) s += __shfl_xor(s, m);
    if ((t & 63) == 0) sw[t >> 6] = s;
    __syncthreads();
    if (t == 0) bsum[blockIdx.x] = sw[0] + sw[1] + sw[2] + sw[3];
}

__global__ __launch_bounds__(256)
void scan_bsum(int* __restrict__ ba, int* __restrict__ bb, int nb) {
    int* b = blockIdx.x ? bb : ba;
    __shared__ int s[256];
    int t = threadIdx.x;
    int v = (t < nb) ? b[t] : 0;
    s[t] = v;
    __syncthreads();
    for (int o = 1; o < 256; o <<= 1) {
        int u = 0;
        if (t >= o) u = s[t - o];
        __syncthreads();
        if (t >= o) s[t] += u;
        __syncthreads();
    }
    if (t < nb) b[t] = s[t] - v;   // exclusive
}

__global__ __launch_bounds__(256)
void scan_apply(const int* __restrict__ c0, const int* __restrict__ b0,
                int* __restrict__ r0, int* __restrict__ cur0,
                const int* __restrict__ c1, const int* __restrict__ b1,
                int* __restrict__ r1, int* __restrict__ cur1, int N, int E) {
    const int* cnt  = blockIdx.y ? c1 : c0;
    const int* bsum = blockIdx.y ? b1 : b0;
    int* rowstart   = blockIdx.y ? r1 : r0;
    int* cursor     = blockIdx.y ? cur1 : cur0;
    __shared__ int sw[4];
    int t = threadIdx.x;
    int base = blockIdx.x * SCB + t * 8;
    int v[8]; int s = 0;
#pragma unroll
    for (int j = 0; j < 8; ++j) { int idx = base + j; v[j] = (idx < N) ? cnt[idx] : 0; s += v[j]; }
    int own = s;
    for (int m = 1; m < 64; m <<= 1) {
        int u = __shfl_up(s, m);
        if ((t & 63) >= m) s += u;
    }
    if ((t & 63) == 63) sw[t >> 6] = s;
    __syncthreads();
    int w = t >> 6, woff = 0;
    if (w > 0) woff += sw[0];
    if (w > 1) woff += sw[1];
    if (w > 2) woff += sw[2];
    int excl = bsum[blockIdx.x] + woff + s - own;
#pragma unroll
    for (int j = 0; j < 8; ++j) {
        int idx = base + j;
        if (idx < N) { rowstart[idx] = excl; excl += v[j]; cursor[idx] = 0; }
    }
    if (blockIdx.x == 0 && t == 0) rowstart[N] = E;
}

__global__ __launch_bounds__(256)
void fill_kernel(const int* __restrict__ ei0, const int* __restrict__ r0,
                 int* __restrict__ cur0, int* __restrict__ e0,
                 const int* __restrict__ ei1, const int* __restrict__ r1,
                 int* __restrict__ cur1, int* __restrict__ e1, int E) {
    const int* ei       = blockIdx.y ? ei1 : ei0;
    const int* rowstart = blockIdx.y ? r1  : r0;
    int* cursor         = blockIdx.y ? cur1 : cur0;
    int* elist          = blockIdx.y ? e1  : e0;
    int e = blockIdx.x * blockDim.x + threadIdx.x;
    if (e < E) {
        int dst = ei[E + e];
        int p = atomicAdd(&cursor[dst], 1);
        elist[rowstart[dst] + p] = ei[e];
    }
}

// ======= FUSED: gather-mean (into LDS) + GEMM + LN + ReLU; dirs via blockIdx.y =======
// r18 structure; phase-1 rewritten with 4 CONCURRENT row-chains per half-wave
// (r18 lesson: serial per-row gather chain at 16 waves/CU exposed full L3 latency).
__global__ __launch_bounds__(GM_TH, 4)
void sage_fused(const unsigned short* __restrict__ xg0, const int* __restrict__ rs0,
                const int* __restrict__ el0, const unsigned short* __restrict__ xd0,
                const unsigned short* __restrict__ Bc0, const float* __restrict__ bl0,
                const float* __restrict__ gm0, const float* __restrict__ bt0,
                float* __restrict__ outf0, unsigned short* __restrict__ outb0,
                const unsigned short* __restrict__ xg1, const int* __restrict__ rs1,
                const int* __restrict__ el1, const unsigned short* __restrict__ xd1,
                const unsigned short* __restrict__ Bc1, const float* __restrict__ bl1,
                const float* __restrict__ gm1, const float* __restrict__ bt1,
                float* __restrict__ outf1, unsigned short* __restrict__ outb1,
                int Nrows)
{
    const int dir = blockIdx.y;
    const unsigned short* xg   = dir ? xg1 : xg0;   // gather source (other type)
    const int* rowstart        = dir ? rs1 : rs0;
    const int* elist           = dir ? el1 : el0;
    const unsigned short* xd   = dir ? xd1 : xd0;   // self features
    const unsigned short* Bcat = dir ? Bc1 : Bc0;
    const float* bl    = dir ? bl1 : bl0;
    const float* gamma = dir ? gm1 : gm0;
    const float* beta  = dir ? bt1 : bt0;
    float* outf          = dir ? outf1 : outf0;
    unsigned short* outb = dir ? outb1 : outb0;

    __shared__ __align__(16) char smem[AME_BYTES + 3 * B_BUF_BYTES];   // 80 KB
    unsigned short* Ame = (unsigned short*)smem;     // [64][256] bf16, swz slots
    char* Bsb = smem + AME_BYTES;

    const int tid  = threadIdx.x;
    const int lane = tid & 63;
    const int wr   = tid >> 8;                 // 0..1 (32-row groups)
    const int wc   = (tid >> 6) & 3;           // 0..3 (64-col groups)
    const int cl   = lane & 15;
    const int g    = lane >> 4;                // 0..3 -> k-chunk
    const long brow = (long)blockIdx.x * GM_BM;

    // B staging coords (r13 verbatim)
    const int colB0 = tid >> 2,          slB0 = tid & 3;
    const int colB1 = (tid + 512) >> 2,  slB1 = tid & 3;
    const int swzB0 = ((slB0 ^ ((colB0 >> 1) & 3)) << 3);
    const int swzB1 = ((slB1 ^ ((colB1 >> 1) & 3)) << 3);

#define STAGE_B(buf, t_)                                                           \
    {                                                                              \
        const int kb_ = (t_) * GM_BK;                                              \
        gload16(Bcat + (size_t)colB0 * KTOT + kb_ + swzB0,                         \
                Bsb + (buf) * B_BUF_BYTES + tid * 16);                             \
        gload16(Bcat + (size_t)colB1 * KTOT + kb_ + swzB1,                         \
                Bsb + (buf) * B_BUF_BYTES + (tid + 512) * 16);                     \
    }

    STAGE_B(0, 0);
    STAGE_B(1, 1);

    // ---- phase 1: gather mean rows into Ame; 4 CONCURRENT row-chains per half-wave ----
    {
        const int hw = tid >> 5;       // 0..15
        const int ln = tid & 31;       // 16B chunk within row
        long grow4[4]; int lo4[4], hi4[4];
#pragma unroll
        for (int r = 0; r < 4; ++r) {
            long gr = brow + hw + r * 16;
            if (gr > (long)Nrows - 1) gr = (long)Nrows - 1;
            grow4[r] = gr;
        }
#pragma unroll
        for (int r = 0; r < 4; ++r) { lo4[r] = rowstart[grow4[r]]; hi4[r] = rowstart[grow4[r] + 1]; }
        float am[4][8];
#pragma unroll
        for (int r = 0; r < 4; ++r)
#pragma unroll
            for (int j = 0; j < 8; ++j) am[r][j] = 0.f;
        int ix0 = lo4[0], ix1 = lo4[1], ix2 = lo4[2], ix3 = lo4[3];
        while (true) {
            bool l0 = ix0 < hi4[0], l1 = ix1 < hi4[1], l2 = ix2 < hi4[2], l3 = ix3 < hi4[3];
            if (!(l0 | l1 | l2 | l3)) break;
            int s0 = 0, s1 = 0, s2 = 0, s3 = 0;
            if (l0) s0 = elist[ix0];
            if (l1) s1 = elist[ix1];
            if (l2) s2 = elist[ix2];
            if (l3) s3 = elist[ix3];
            bf16x8 v0, v1, v2, v3;
            if (l0) v0 = *((const bf16x8*)(xg + (size_t)s0 * CCH) + ln);
            if (l1) v1 = *((const bf16x8*)(xg + (size_t)s1 * CCH) + ln);
            if (l2) v2 = *((const bf16x8*)(xg + (size_t)s2 * CCH) + ln);
            if (l3) v3 = *((const bf16x8*)(xg + (size_t)s3 * CCH) + ln);
            if (l0) {
#pragma unroll
                for (int j = 0; j < 8; ++j) am[0][j] += bf2f(v0[j]);
                ++ix0;
            }
            if (l1) {
#pragma unroll
                for (int j = 0; j < 8; ++j) am[1][j] += bf2f(v1[j]);
                ++ix1;
            }
            if (l2) {
#pragma unroll
                for (int j = 0; j < 8; ++j) am[2][j] += bf2f(v2[j]);
                ++ix2;
            }
            if (l3) {
#pragma unroll
                for (int j = 0; j < 8; ++j) am[3][j] += bf2f(v3[j]);
                ++ix3;
            }
        }
#pragma unroll
        for (int r = 0; r < 4; ++r) {
            int row = hw + r * 16;
            float rr = (hi4[r] > lo4[r]) ? 1.0f / (float)(hi4[r] - lo4[r]) : 0.0f;
            bf16x8 pk;
#pragma unroll
            for (int j = 0; j < 8; ++j) pk[j] = (short)f2bf(am[r][j] * rr);
            *(bf16x8*)&Ame[row * CCH + ((ln ^ (row & 7)) << 3)] = pk;
        }
    }
    __syncthreads();   // Ame ready; drains B0/B1 too (fine)

    f32x4 acc[2][4];
#pragma unroll
    for (int m = 0; m < 2; ++m)
#pragma unroll
        for (int n = 0; n < 4; ++n) acc[m][n] = (f32x4){0.f, 0.f, 0.f, 0.f};

    const int hw = tid >> 5;
    const int ln = tid & 31;
    for (int t = 0; t < 16; ++t) {
        if (t == 8) {
            // Ame dead (t=7's end barrier passed) -> restage with xdst rows.
            // Dest = wave-uniform + lane*16 (legal); swizzle on per-lane SOURCE.
#pragma unroll
            for (int j = 0; j < 4; ++j) {
                int row = hw + j * 16;
                long grow = brow + row; if (grow > (long)Nrows - 1) grow = (long)Nrows - 1;
                gload16(xd + grow * CCH + ((ln ^ (hw & 7)) << 3),
                        (char*)Ame + (size_t)(row * 32 + ln) * 16);
            }
            STAGE_B(1, 10);   // 10 % 3 == 1
            asm volatile("s_waitcnt vmcnt(2)" ::: "memory");   // B9 + A landed; B10 in flight
            __builtin_amdgcn_s_barrier();
            __builtin_amdgcn_sched_barrier(0);
        } else if (t + 2 < 16) {
            STAGE_B((t + 2) % 3, t + 2);
        }
        const char* Bb = Bsb + (t % 3) * B_BUF_BYTES;
        const int ct = (t & 7) * 4 + g;            // chunk within 256-elem A row
        bf16x8 a[2], b[4];
#pragma unroll
        for (int m = 0; m < 2; ++m) {
            int row = wr * 32 + m * 16 + cl;
            int slot = ct ^ (cl & 7);
            a[m] = *(const bf16x8*)&Ame[row * CCH + slot * 8];
        }
#pragma unroll
        for (int n = 0; n < 4; ++n) {
            int col = wc * 64 + n * 16 + cl;
            int slot = g ^ ((col >> 1) & 3);
            b[n] = *(const bf16x8*)(Bb + col * 64 + slot * 16);
        }
#pragma unroll
        for (int m = 0; m < 2; ++m)
#pragma unroll
            for (int n = 0; n < 4; ++n)
                acc[m][n] = __builtin_amdgcn_mfma_f32_16x16x32_bf16(a[m], b[n], acc[m][n], 0, 0, 0);
        // race fence (rule #18): ds_reads returned before barrier
        asm volatile("s_waitcnt lgkmcnt(0)" ::: "memory");
        __builtin_amdgcn_sched_barrier(0);
        if (t < 13) asm volatile("s_waitcnt vmcnt(2)" ::: "memory");
        else        asm volatile("s_waitcnt vmcnt(0)" ::: "memory");
        __builtin_amdgcn_s_barrier();
        __builtin_amdgcn_sched_barrier(0);
    }
#undef STAGE_B

    // ---- epilogue: +bias, cross-wave LayerNorm, ReLU, store ----
    float p1[2][4], p2[2][4];
#pragma unroll
    for (int m = 0; m < 2; ++m)
#pragma unroll
        for (int j = 0; j < 4; ++j) { p1[m][j] = 0.f; p2[m][j] = 0.f; }
#pragma unroll
    for (int n = 0; n < 4; ++n) {
        float bv = bl[wc * 64 + n * 16 + cl];
#pragma unroll
        for (int m = 0; m < 2; ++m)
#pragma unroll
            for (int j = 0; j < 4; ++j) {
                float v = acc[m][n][j] + bv;
                acc[m][n][j] = v;
                p1[m][j] += v;
                p2[m][j] += v * v;
            }
    }
#pragma unroll
    for (int msk = 1; msk < 16; msk <<= 1) {
#pragma unroll
        for (int m = 0; m < 2; ++m)
#pragma unroll
            for (int j = 0; j < 4; ++j) {
                p1[m][j] += __shfl_xor(p1[m][j], msk);
                p2[m][j] += __shfl_xor(p2[m][j], msk);
            }
    }
    float2* red = (float2*)smem;   // red[64][4], 2 KB overlay (fully drained)
    if (cl == 0) {
#pragma unroll
        for (int m = 0; m < 2; ++m)
#pragma unroll
            for (int j = 0; j < 4; ++j) {
                int rl = wr * 32 + m * 16 + g * 4 + j;
                red[rl * 4 + wc] = make_float2(p1[m][j], p2[m][j]);
            }
    }
    __syncthreads();

    float gmv[4], btv[4];
#pragma unroll
    for (int n = 0; n < 4; ++n) {
        gmv[n] = gamma[wc * 64 + n * 16 + cl];
        btv[n] = beta[wc * 64 + n * 16 + cl];
    }
#pragma unroll
    for (int m = 0; m < 2; ++m) {
#pragma unroll
        for (int j = 0; j < 4; ++j) {
            int rl = wr * 32 + m * 16 + g * 4 + j;
            f32x4 u0 = *(const f32x4*)&red[rl * 4 + 0];
            f32x4 u1 = *(const f32x4*)&red[rl * 4 + 2];
            float s1 = u0[0] + u0[2] + u1[0] + u1[2];
            float s2 = u0[1] + u0[3] + u1[1] + u1[3];
            float mu = s1 * (1.0f / CCH);
            float var = s2 * (1.0f / CCH) - mu * mu;
            float rsd = rsqrtf(var + 1e-5f);
            long r = brow + rl;
            if (r < Nrows) {
#pragma unroll
                for (int n = 0; n < 4; ++n) {
                    float v = (acc[m][n][j] - mu) * rsd * gmv[n] + btv[n];
                    v = fmaxf(v, 0.f);
                    long off = r * CCH + wc * 64 + n * 16 + cl;
                    if (outf) outf[off] = v;
                    if (outb) outb[off] = f2bf(v);
                }
            }
        }
    }
}

extern "C" void kernel_launch(void* const* d_in, const int* in_sizes, int n_in,
                              void* d_out, int out_size, void* d_ws, size_t ws_size,
                              hipStream_t stream) {
    const float* x_user = (const float*)d_in[0];
    const float* x_item = (const float*)d_in[1];
    const int*   ei_u2i = (const int*)d_in[2];
    const int*   ei_i2u = (const int*)d_in[3];
    const float* Wl_u2i = (const float*)d_in[4];
    const float* bl_u2i = (const float*)d_in[5];
    const float* Wr_u2i = (const float*)d_in[6];
    const float* Wl_i2u = (const float*)d_in[7];
    const float* bl_i2u = (const float*)d_in[8];
    const float* Wr_i2u = (const float*)d_in[9];
    const float* g_user = (const float*)d_in[10];
    const float* b_user = (const float*)d_in[11];
    const float* g_item = (const float*)d_in[12];
    const float* b_item = (const float*)d_in[13];

    const int N = in_sizes[0] / CCH;
    const int E = in_sizes[2] / 2;
    const size_t NC = (size_t)N * CCH;
    const int nb = (N + SCB - 1) / SCB;

    // workspace layout (~210 MB)
    char* p = (char*)d_ws;
    unsigned short* xb_u = (unsigned short*)p; p += NC * sizeof(unsigned short);   // layer-1 input
    unsigned short* xb_i = (unsigned short*)p; p += NC * sizeof(unsigned short);
    unsigned short* xo_u = (unsigned short*)p; p += NC * sizeof(unsigned short);   // layer-1 output
    unsigned short* xo_i = (unsigned short*)p; p += NC * sizeof(unsigned short);
    unsigned short* wc_u2i = (unsigned short*)p; p += (size_t)2 * CCH * KTOT * sizeof(unsigned short);
    unsigned short* wc_i2u = (unsigned short*)p; p += (size_t)2 * CCH * KTOT * sizeof(unsigned short);
    int* cnt_i  = (int*)p; p += (size_t)N * sizeof(int);   // doubles as fill cursor
    int* cnt_u  = (int*)p; p += (size_t)N * sizeof(int);
    int* rs_i   = (int*)p; p += (size_t)(N + 1) * sizeof(int);
    int* rs_u   = (int*)p; p += (size_t)(N + 1) * sizeof(int);
    int* el_i   = (int*)p; p += (size_t)E * sizeof(int);
    int* el_u   = (int*)p; p += (size_t)E * sizeof(int);
    int* bs_i   = (int*)p; p += 256 * sizeof(int);
    int* bs_u   = (int*)p; p += 256 * sizeof(int);

    float* out_user = (float*)d_out;
    float* out_item = out_user + NC;

    const int eb = (E + 255) / 256;
    const int cb = (int)((NC / 8 + 255) / 256);
    const int gm_blocks = (N + GM_BM - 1) / GM_BM;

    // ---- CSR build ----
    hipMemsetAsync(cnt_i, 0, (size_t)2 * N * sizeof(int), stream);
    hist_kernel<<<dim3(eb, 2), 256, 0, stream>>>(ei_u2i, cnt_i, ei_i2u, cnt_u, E);
    scan_part<<<dim3(nb, 2), 256, 0, stream>>>(cnt_i, bs_i, cnt_u, bs_u, N);
    scan_bsum<<<2, 256, 0, stream>>>(bs_i, bs_u, nb);
    scan_apply<<<dim3(nb, 2), 256, 0, stream>>>(cnt_i, bs_i, rs_i, cnt_i,
                                                cnt_u, bs_u, rs_u, cnt_u, N, E);
    fill_kernel<<<dim3(eb, 2), 256, 0, stream>>>(ei_u2i, rs_i, cnt_i, el_i,
                                                 ei_i2u, rs_u, cnt_u, el_u, E);

    // ---- weight concat + bf16 ----
    cvt_wcat<<<dim3(32, 4), 256, 0, stream>>>(Wl_u2i, Wr_u2i, wc_u2i,
                                              Wl_i2u, Wr_i2u, wc_i2u);

    // ---- bf16 copies of inputs ----
    cvt_bf16<<<dim3(cb, 2), 256, 0, stream>>>(x_user, xb_u, x_item, xb_i, (long)NC);

    // ---- layer 1: reads xb_*, writes xo_* (bf16) ----
    sage_fused<<<dim3(gm_blocks, 2), GM_TH, 0, stream>>>(
        xb_u, rs_i, el_i, xb_i, wc_u2i, bl_u2i, g_item, b_item, nullptr, xo_i,
        xb_i, rs_u, el_u, xb_u, wc_i2u, bl_i2u, g_user, b_user, nullptr, xo_u, N);

    // ---- layer 2: reads xo_*, writes d_out (fp32) ----
    sage_fused<<<dim3(gm_blocks, 2), GM_TH, 0, stream>>>(
        xo_u, rs_i, el_i, xo_i, wc_u2i + (size_t)CCH * KTOT, bl_u2i + CCH,
        g_item + CCH, b_item + CCH, out_item, nullptr,
        xo_i, rs_u, el_u, xo_u, wc_i2u + (size_t)CCH * KTOT, bl_i2u + CCH,
        g_user + CCH, b_user + CCH, out_user, nullptr, N);
}